// Round 7
// baseline (275.429 us; speedup 1.0000x reference)
//
#include <hip/hip_runtime.h>
#include <cstdint>
#include <cstddef>

#define DM 2048
#define TT 2048
#define BB 2
#define HQ 16
#define HKV 4
#define HD 128

typedef _Float16 f16;
using f16x8 = __attribute__((ext_vector_type(8))) f16;
using f32x4 = __attribute__((ext_vector_type(4))) float;
using f32x16 = __attribute__((ext_vector_type(16))) float;
using u32x4 = __attribute__((ext_vector_type(4))) uint32_t;

#define MFMA16(a, b, c) __builtin_amdgcn_mfma_f32_16x16x32_f16(a, b, c, 0, 0, 0)
#define MFMA32(a, b, c) __builtin_amdgcn_mfma_f32_32x32x16_f16(a, b, c, 0, 0, 0)

static __device__ __forceinline__ float fast_exp2(float x) {
#if __has_builtin(__builtin_amdgcn_exp2f)
  return __builtin_amdgcn_exp2f(x);
#else
  return exp2f(x);
#endif
}

static __device__ __forceinline__ uint32_t cvt_pk_u32(float a, float b) {
  auto h2 = __builtin_amdgcn_cvt_pkrtz(a, b);
  return __builtin_bit_cast(uint32_t, h2);
}

// ---------------- fp32 -> fp16 convert (vectorized) ----------------
__global__ __launch_bounds__(256) void k_cvt_f16(const float* __restrict__ in,
                                                 f16* __restrict__ out, int n8) {
  int i = blockIdx.x * 256 + threadIdx.x;
  if (i >= n8) return;
  const float4* pin = (const float4*)in;
  float4 a = pin[2 * i], b = pin[2 * i + 1];
  f16x8 o = {(f16)a.x, (f16)a.y, (f16)a.z, (f16)a.w,
             (f16)b.x, (f16)b.y, (f16)b.z, (f16)b.w};
  *(f16x8*)&out[(size_t)8 * i] = o;
}

// ------------- transpose + convert: in fp32 [K][N] -> out f16 [N][K] -------------
__global__ __launch_bounds__(256) void k_tr_cvt(const float* __restrict__ in,
                                                f16* __restrict__ out, int N, int ldout) {
  __shared__ float tile[32][33];
  int n0 = blockIdx.x * 32, k0 = blockIdx.y * 32;
  int tx = threadIdx.x, ty = threadIdx.y;
#pragma unroll
  for (int r = 0; r < 32; r += 8) tile[ty + r][tx] = in[(size_t)(k0 + ty + r) * N + n0 + tx];
  __syncthreads();
#pragma unroll
  for (int r = 0; r < 32; r += 8)
    out[(size_t)(n0 + ty + r) * ldout + k0 + tx] = (f16)tile[tx][ty + r];
}

// ---------------- MFMA GEMM: C[M,N] = A[M,K] * BT[N,K]^T ----------------
template <int N_, bool OUT_F16>
__global__ __launch_bounds__(256) void k_gemm(const f16* __restrict__ A,
                                              const f16* __restrict__ BT,
                                              void* __restrict__ Cp, int M, int K) {
  constexpr int BK = 64;
  __shared__ alignas(16) f16 As[128][72];
  __shared__ alignas(16) f16 Bs[128][72];
  constexpr int NT = N_ / 128;
  int bid = blockIdx.x;
  int m0 = (bid / NT) * 128, n0 = (bid % NT) * 128;
  int tid = threadIdx.x;
  int lane = tid & 63, w = tid >> 6;
  int wm = (w >> 1) * 64, wn = (w & 1) * 64;
  int g = lane >> 4, c = lane & 15;
  int sr = tid >> 3, sc = (tid & 7) * 8;
  f32x4 acc[4][4] = {};
  for (int k0 = 0; k0 < K; k0 += BK) {
#pragma unroll
    for (int i = 0; i < 4; i++) {
      int r = sr + 32 * i;
      *(uint4*)&As[r][sc] = *(const uint4*)&A[(size_t)(m0 + r) * K + k0 + sc];
      *(uint4*)&Bs[r][sc] = *(const uint4*)&BT[(size_t)(n0 + r) * K + k0 + sc];
    }
    __syncthreads();
#pragma unroll
    for (int ks = 0; ks < 2; ks++) {
      f16x8 af[4], bf[4];
#pragma unroll
      for (int mm = 0; mm < 4; mm++) af[mm] = *(const f16x8*)&As[wm + mm * 16 + c][ks * 32 + g * 8];
#pragma unroll
      for (int nn = 0; nn < 4; nn++) bf[nn] = *(const f16x8*)&Bs[wn + nn * 16 + c][ks * 32 + g * 8];
#pragma unroll
      for (int mm = 0; mm < 4; mm++)
#pragma unroll
        for (int nn = 0; nn < 4; nn++)
          acc[mm][nn] = MFMA16(af[mm], bf[nn], acc[mm][nn]);
    }
    __syncthreads();
  }
  int gg = lane >> 4, cc = lane & 15;
#pragma unroll
  for (int mm = 0; mm < 4; mm++)
#pragma unroll
    for (int nn = 0; nn < 4; nn++)
#pragma unroll
      for (int r = 0; r < 4; r++) {
        size_t row = m0 + wm + mm * 16 + gg * 4 + r;
        size_t col = n0 + wn + nn * 16 + cc;
        float v = acc[mm][nn][r];
        if constexpr (OUT_F16)
          ((f16*)Cp)[row * N_ + col] = (f16)v;
        else
          ((float*)Cp)[row * N_ + col] = v;
      }
}

// ---------------- RMSNorm + RoPE + relayout (Q, K only) ----------------
__global__ __launch_bounds__(256) void k_norm_rope(const f16* __restrict__ qkv,
                                                   const int* __restrict__ pos_ids,
                                                   const float* __restrict__ qw,
                                                   const float* __restrict__ kw,
                                                   f16* __restrict__ Qo, f16* __restrict__ Ko) {
  int bt = blockIdx.x;
  int b = bt >> 11, t = bt & 2047;
  int tid = threadIdx.x, w = tid >> 6, lane = tid & 63;
  const f16* row = qkv + (size_t)bt * 3072;
  float pq = (float)pos_ids[t];
  float pk = (float)t;
  float inv = expf(-(float)lane * 0.14391156831212787f);
  for (int hi = w; hi < 20; hi += 4) {
    bool isq = hi < 16;
    int off = isq ? hi * 128 : 2048 + (hi - 16) * 128;
    float x1 = (float)row[off + 2 * lane];
    float x2 = (float)row[off + 2 * lane + 1];
    float ss = x1 * x1 + x2 * x2;
#pragma unroll
    for (int o = 1; o < 64; o <<= 1) ss += __shfl_xor(ss, o);
    float rms = rsqrtf(ss * (1.0f / 128.0f) + 1e-6f);
    const float* wt = isq ? qw : kw;
    float n1 = x1 * rms * wt[2 * lane], n2 = x2 * rms * wt[2 * lane + 1];
    float pos = isq ? pq : pk;
    float ang = pos * inv;
    float sn = sinf(ang), cs = cosf(ang);
    f16 r1 = (f16)(n1 * cs - n2 * sn), r2 = (f16)(n1 * sn + n2 * cs);
    if (isq) {
      f16* dst = Qo + (((size_t)b * HQ + hi) * TT + t) * HD;
      dst[2 * lane] = r1;
      dst[2 * lane + 1] = r2;
    } else {
      f16* dst = Ko + (((size_t)b * HKV + (hi - 16)) * TT + t) * HD;
      dst[2 * lane] = r1;
      dst[2 * lane + 1] = r2;
    }
  }
}

// ------- V transpose: from QKV buffer cols [2560..3072) -> Vt[b][hkv][d][t] -------
__global__ __launch_bounds__(256) void k_trV(const f16* __restrict__ qkv,
                                             f16* __restrict__ Vt) {
  __shared__ f16 tile[32][34];
  int t0 = blockIdx.x * 32, d0 = blockIdx.y * 32;
  int bh = blockIdx.z;
  int b = bh >> 2, hkv = bh & 3;
  int tx = threadIdx.x, ty = threadIdx.y;
  const f16* src = qkv + (size_t)b * 2048 * 3072 + 2560 + hkv * 128;
#pragma unroll
  for (int r = 0; r < 32; r += 8)
    tile[ty + r][tx] = src[(size_t)(t0 + ty + r) * 3072 + d0 + tx];
  __syncthreads();
  f16* dst = Vt + ((size_t)bh * HD + d0) * TT + t0;
#pragma unroll
  for (int r = 0; r < 32; r += 8)
    dst[(size_t)(ty + r) * TT + tx] = tile[tx][ty + r];
}

// ---- attention (round-3 geometry): 4 waves x 32q, 64-key tiles, swapped QK^T ----
// Fragment build via __shfl_xor (modeled, convergent) instead of permlane asm/union.
__global__ __launch_bounds__(256, 2) void k_attn2(const f16* __restrict__ Q,
                                                  const f16* __restrict__ Kc,
                                                  const f16* __restrict__ Vt,
                                                  f16* __restrict__ Oa) {
  __shared__ alignas(16) char KsC[64 * 256];   // K tile: 64 keys x 128 d, swz8
  __shared__ alignas(16) char VsC[128 * 128];  // V^T tile: 128 d x 64 keys, swz8
  int qt = blockIdx.x, h = blockIdx.y, b = blockIdx.z;
  int q0 = qt * 128, hkv = h >> 2;
  int tid = threadIdx.x;
  int w = tid >> 6, lane = tid & 63, ln = lane & 31, hi = lane >> 5;
  const f16* Kb = Kc + ((size_t)b * HKV + hkv) * TT * HD;
  const f16* Vb = Vt + ((size_t)b * HKV + hkv) * (size_t)HD * TT;
  int q = q0 + w * 32 + ln;
  const f16* Qp = Q + (((size_t)b * HQ + h) * TT + q) * HD + hi * 8;
  f16x8 qf[8];
#pragma unroll
  for (int st = 0; st < 8; st++) qf[st] = *(const f16x8*)&Qp[st * 16];
  f32x16 o[4] = {};
  float lsum = 0.f;
  int kr = tid >> 2, kqb = (tid & 3) * 64;  // K stage: 4 threads/row, 64B each
  int vr = tid >> 1, vqb = (tid & 1) * 64;  // V stage: 2 threads/row, 64B each
  int kswz = (kr & 7) << 4, vswz = (vr & 7) << 4;
  int kfswz = (ln & 7) << 4;

  int k0max = (q0 + 127) & ~63;
  int wlo = (q0 - 1023 > 128) ? ((q0 - 1023) & ~63) : 128;
  int nw = (k0max >= wlo) ? ((k0max - wlo) >> 6) + 1 : 0;
  int ntiles = 2 + nw;
  int qw = q0 + w * 32;

  const float C1 = 0.12751791217100872f;  // (1/sqrt(128)) * log2(e)
  const float C2 = 5.7707801635534255f;   // 4.0 * log2(e)  (fixed softmax shift)

  uint4 kreg[4], vreg[4];
  {  // prologue: load + store tile 0 (k0 = 0)
    const char* kp = (const char*)(Kb + (size_t)kr * HD);
#pragma unroll
    for (int i = 0; i < 4; i++) kreg[i] = *(const uint4*)(kp + kqb + i * 16);
    const char* vp = (const char*)(Vb + (size_t)vr * TT);
#pragma unroll
    for (int i = 0; i < 4; i++) vreg[i] = *(const uint4*)(vp + vqb + i * 16);
    char* kd = KsC + kr * 256;
#pragma unroll
    for (int i = 0; i < 4; i++) *(uint4*)(kd + ((kqb + i * 16) ^ kswz)) = kreg[i];
    char* vd = VsC + vr * 128;
#pragma unroll
    for (int i = 0; i < 4; i++) *(uint4*)(vd + ((vqb + i * 16) ^ vswz)) = vreg[i];
  }
  __syncthreads();

  for (int ti = 0; ti < ntiles; ti++) {
    int k0 = (ti < 2) ? ti * 64 : wlo + (ti - 2) * 64;
    bool havenext = (ti + 1 < ntiles);
    if (havenext) {  // issue next tile's loads; latency hides under MFMA
      int k0n = (ti + 1 < 2) ? 64 : wlo + (ti - 1) * 64;
      const char* kp = (const char*)(Kb + (size_t)(k0n + kr) * HD);
#pragma unroll
      for (int i = 0; i < 4; i++) kreg[i] = *(const uint4*)(kp + kqb + i * 16);
      const char* vp = (const char*)(Vb + (size_t)vr * TT + (size_t)k0n);
#pragma unroll
      for (int i = 0; i < 4; i++) vreg[i] = *(const uint4*)(vp + vqb + i * 16);
    }
    bool needmask = false;
    if (ti >= 2) {
      int wsmax = qw + 31 - 1023;
      if (wsmax < 128) wsmax = 128;
      needmask = !((k0 + 63 <= qw) && (k0 >= wsmax));
    }
    f16x8 pa[2][2];
#pragma unroll
    for (int ksub = 0; ksub < 2; ksub++) {
      f32x16 s = {};
      const char* krow = KsC + (ksub * 32 + ln) * 256;
#pragma unroll
      for (int st = 0; st < 8; st++) {
        f16x8 kf = *(const f16x8*)(krow + ((st * 32 + hi * 16) ^ kfswz));
        s = MFMA32(kf, qf[st], s);  // S^T: lane col = q, regs = keys
      }
      int qmk = q - (k0 + ksub * 32 + 4 * hi);
      float pr[16];
#pragma unroll
      for (int r = 0; r < 16; r++) {
        float e = fast_exp2(s[r] * C1 - C2);
        if (needmask) {
          int kk = (r & 3) + 8 * (r >> 2);
          e = ((uint32_t)(qmk - kk) < 1024u) ? e : 0.0f;
        }
        lsum += e;
        pr[r] = e;
      }
      uint32_t c[8];
#pragma unroll
      for (int i = 0; i < 8; i++) c[i] = cvt_pk_u32(pr[2 * i], pr[2 * i + 1]);
      // Build PV A-fragments via shfl_xor(32) + per-lane select (no asm, no alloca).
      // hi=0 lane needs keys {0..7}: own c0,c1 then partner c0,c1.
      // hi=1 lane needs keys {8..15}: partner c2,c3 then own c2,c3.
      {
        uint32_t x0 = __shfl_xor(c[0], 32), x1 = __shfl_xor(c[1], 32);
        uint32_t x2 = __shfl_xor(c[2], 32), x3 = __shfl_xor(c[3], 32);
        u32x4 t0 = {hi ? x2 : c[0], hi ? x3 : c[1], hi ? c[2] : x0, hi ? c[3] : x1};
        pa[ksub][0] = __builtin_bit_cast(f16x8, t0);
        uint32_t x4 = __shfl_xor(c[4], 32), x5 = __shfl_xor(c[5], 32);
        uint32_t x6 = __shfl_xor(c[6], 32), x7 = __shfl_xor(c[7], 32);
        u32x4 t1 = {hi ? x6 : c[4], hi ? x7 : c[5], hi ? c[6] : x4, hi ? c[7] : x5};
        pa[ksub][1] = __builtin_bit_cast(f16x8, t1);
      }
    }
    // PV: o[q][d] += P[q][k] V[k][d]
#pragma unroll
    for (int dsub = 0; dsub < 4; dsub++) {
      const char* vrow = VsC + (dsub * 32 + ln) * 128;
#pragma unroll
      for (int ksub = 0; ksub < 2; ksub++)
#pragma unroll
        for (int st2 = 0; st2 < 2; st2++) {
          f16x8 vf = *(const f16x8*)(vrow + ((ksub * 64 + st2 * 32 + hi * 16) ^ kfswz));
          o[dsub] = MFMA32(pa[ksub][st2], vf, o[dsub]);
        }
    }
    __syncthreads();
    if (havenext) {
      char* kd = KsC + kr * 256;
#pragma unroll
      for (int i = 0; i < 4; i++) *(uint4*)(kd + ((kqb + i * 16) ^ kswz)) = kreg[i];
      char* vd = VsC + vr * 128;
#pragma unroll
      for (int i = 0; i < 4; i++) *(uint4*)(vd + ((vqb + i * 16) ^ vswz)) = vreg[i];
    }
    __syncthreads();
  }
  // epilogue: finish l, scale, store
  lsum += __shfl_xor(lsum, 32);
  float rl[16];
#pragma unroll
  for (int r = 0; r < 16; r++) {
    int row = (r & 3) + 8 * (r >> 2) + 4 * hi;
    float lv = __shfl(lsum, row);
    rl[r] = 1.0f / lv;
  }
#pragma unroll
  for (int r = 0; r < 16; r++) {
    int row = (r & 3) + 8 * (r >> 2) + 4 * hi;
    size_t base = ((size_t)b * TT + q0 + w * 32 + row) * DM + (size_t)h * HD + ln;
#pragma unroll
    for (int dsub = 0; dsub < 4; dsub++)
      Oa[base + dsub * 32] = (f16)(o[dsub][r] * rl[r]);
  }
}

extern "C" void kernel_launch(void* const* d_in, const int* in_sizes, int n_in,
                              void* d_out, int out_size, void* d_ws, size_t ws_size,
                              hipStream_t stream) {
  const float* hidden = (const float*)d_in[0];
  const int* pos = (const int*)d_in[1];
  const float* Wq = (const float*)d_in[2];
  const float* Wk = (const float*)d_in[3];
  const float* Wv = (const float*)d_in[4];
  const float* Wo = (const float*)d_in[5];
  const float* qw = (const float*)d_in[6];
  const float* kw = (const float*)d_in[7];
  float* out = (float*)d_out;

  char* p = (char*)d_ws;
  auto take = [&](size_t n) {
    void* r = (void*)p;
    p += (n + 255) & ~(size_t)255;
    return r;
  };
  f16* Xb = (f16*)take((size_t)4096 * 2048 * 2);
  f16* WqkvT = (f16*)take((size_t)3072 * 2048 * 2);
  f16* WoT = (f16*)take((size_t)2048 * 2048 * 2);
  f16* QKVb = (f16*)take((size_t)4096 * 3072 * 2);
  f16* Qr = (f16*)take((size_t)BB * HQ * TT * HD * 2);
  f16* Kr = (f16*)take((size_t)BB * HKV * TT * HD * 2);
  f16* Vt = (f16*)take((size_t)BB * HKV * TT * HD * 2);
  f16* Attn = (f16*)take((size_t)4096 * 2048 * 2);

  dim3 tb(32, 8);
  k_cvt_f16<<<4096, 256, 0, stream>>>(hidden, Xb, 1048576);
  k_tr_cvt<<<dim3(64, 64), tb, 0, stream>>>(Wq, WqkvT, 2048, 2048);
  k_tr_cvt<<<dim3(16, 64), tb, 0, stream>>>(Wk, WqkvT + (size_t)2048 * 2048, 512, 2048);
  k_tr_cvt<<<dim3(16, 64), tb, 0, stream>>>(Wv, WqkvT + (size_t)2560 * 2048, 512, 2048);
  k_tr_cvt<<<dim3(64, 64), tb, 0, stream>>>(Wo, WoT, 2048, 2048);
  k_gemm<3072, true><<<768, 256, 0, stream>>>(Xb, WqkvT, QKVb, 4096, 2048);
  k_norm_rope<<<4096, 256, 0, stream>>>(QKVb, pos, qw, kw, Qr, Kr);
  k_trV<<<dim3(64, 4, 8), tb, 0, stream>>>(QKVb, Vt);
  k_attn2<<<dim3(16, 16, 2), 256, 0, stream>>>(Qr, Kr, Vt, Attn);
  k_gemm<2048, false><<<512, 256, 0, stream>>>(Attn, WoT, out, 4096, 2048);
}

// Round 8
// 244.713 us; speedup vs baseline: 1.1255x; 1.1255x over previous
//
#include <hip/hip_runtime.h>
#include <cstdint>
#include <cstddef>

#define DM 2048
#define TT 2048
#define BB 2
#define HQ 16
#define HKV 4
#define HD 128

typedef _Float16 f16;
using f16x8 = __attribute__((ext_vector_type(8))) f16;
using f32x4 = __attribute__((ext_vector_type(4))) float;
using f32x16 = __attribute__((ext_vector_type(16))) float;
using u32x4 = __attribute__((ext_vector_type(4))) uint32_t;

#define MFMA16(a, b, c) __builtin_amdgcn_mfma_f32_16x16x32_f16(a, b, c, 0, 0, 0)
#define MFMA32(a, b, c) __builtin_amdgcn_mfma_f32_32x32x16_f16(a, b, c, 0, 0, 0)

typedef __attribute__((address_space(1))) const void gvoid_t;
typedef __attribute__((address_space(3))) void lvoid_t;
static __device__ __forceinline__ void gload16(const void* g, void* l) {
  __builtin_amdgcn_global_load_lds((gvoid_t*)g, (lvoid_t*)l, 16, 0, 0);
}

static __device__ __forceinline__ float fast_exp2(float x) {
#if __has_builtin(__builtin_amdgcn_exp2f)
  return __builtin_amdgcn_exp2f(x);
#else
  return exp2f(x);
#endif
}

static __device__ __forceinline__ uint32_t cvt_pk_u32(float a, float b) {
  auto h2 = __builtin_amdgcn_cvt_pkrtz(a, b);
  return __builtin_bit_cast(uint32_t, h2);
}

// ---------------- fp32 -> fp16 convert (vectorized) ----------------
__global__ __launch_bounds__(256) void k_cvt_f16(const float* __restrict__ in,
                                                 f16* __restrict__ out, int n8) {
  int i = blockIdx.x * 256 + threadIdx.x;
  if (i >= n8) return;
  const float4* pin = (const float4*)in;
  float4 a = pin[2 * i], b = pin[2 * i + 1];
  f16x8 o = {(f16)a.x, (f16)a.y, (f16)a.z, (f16)a.w,
             (f16)b.x, (f16)b.y, (f16)b.z, (f16)b.w};
  *(f16x8*)&out[(size_t)8 * i] = o;
}

// ------------- transpose + convert: in fp32 [K][N] -> out f16 [N][K] -------------
__global__ __launch_bounds__(256) void k_tr_cvt(const float* __restrict__ in,
                                                f16* __restrict__ out, int N, int ldout) {
  __shared__ float tile[32][33];
  int n0 = blockIdx.x * 32, k0 = blockIdx.y * 32;
  int tx = threadIdx.x, ty = threadIdx.y;
#pragma unroll
  for (int r = 0; r < 32; r += 8) tile[ty + r][tx] = in[(size_t)(k0 + ty + r) * N + n0 + tx];
  __syncthreads();
#pragma unroll
  for (int r = 0; r < 32; r += 8)
    out[(size_t)(n0 + ty + r) * ldout + k0 + tx] = (f16)tile[tx][ty + r];
}

// ------- MFMA GEMM (m97 structure): C[M,N] = A[M,K] * BT[N,K]^T, global_load_lds -------
template <int N_, bool OUT_F16>
__global__ __launch_bounds__(256) void k_gemm(const f16* __restrict__ A,
                                              const f16* __restrict__ BT,
                                              void* __restrict__ Cp, int M, int K) {
  __shared__ alignas(16) f16 As[128 * 64];
  __shared__ alignas(16) f16 Bs[128 * 64];
  constexpr int NT = N_ / 128;
  int bid = blockIdx.x;
  int m0 = (bid / NT) * 128, n0 = (bid % NT) * 128;
  int tid = threadIdx.x;
  int lane = tid & 63, w = tid >> 6;
  int wm = (w >> 1) * 64, wn = (w & 1) * 64;
  int g = lane >> 4, c = lane & 15;
  int srow = tid >> 3, scol = (tid & 7) * 8;  // 32 rows/issue, 8 col-slots of 8 f16
  const f16* Ag = A + (size_t)(m0 + srow) * K + scol;
  const f16* Bg = BT + (size_t)(n0 + srow) * K + scol;
  f16* Asw = As + w * 512;  // wave-uniform LDS base (f16 elems); +i*2048 per issue
  f16* Bsw = Bs + w * 512;
  f32x4 acc[4][4] = {};
  for (int k0 = 0; k0 < K; k0 += 64) {
#pragma unroll
    for (int i = 0; i < 4; i++) {
      gload16(Ag + (size_t)(i * 32) * K + k0, Asw + i * 2048);
      gload16(Bg + (size_t)(i * 32) * K + k0, Bsw + i * 2048);
    }
    __syncthreads();
#pragma unroll
    for (int ks = 0; ks < 2; ks++) {
      f16x8 af[4], bf[4];
#pragma unroll
      for (int mm = 0; mm < 4; mm++)
        af[mm] = *(const f16x8*)&As[(wm + mm * 16 + c) * 64 + ks * 32 + g * 8];
#pragma unroll
      for (int nn = 0; nn < 4; nn++)
        bf[nn] = *(const f16x8*)&Bs[(wn + nn * 16 + c) * 64 + ks * 32 + g * 8];
#pragma unroll
      for (int mm = 0; mm < 4; mm++)
#pragma unroll
        for (int nn = 0; nn < 4; nn++)
          acc[mm][nn] = MFMA16(af[mm], bf[nn], acc[mm][nn]);
    }
    __syncthreads();
  }
  int gg = lane >> 4, cc = lane & 15;
#pragma unroll
  for (int mm = 0; mm < 4; mm++)
#pragma unroll
    for (int nn = 0; nn < 4; nn++)
#pragma unroll
      for (int r = 0; r < 4; r++) {
        size_t row = m0 + wm + mm * 16 + gg * 4 + r;
        size_t col = n0 + wn + nn * 16 + cc;
        float v = acc[mm][nn][r];
        if constexpr (OUT_F16)
          ((f16*)Cp)[row * N_ + col] = (f16)v;
        else
          ((float*)Cp)[row * N_ + col] = v;
      }
}

// ---------------- RMSNorm + RoPE + relayout (Q, K only) ----------------
__global__ __launch_bounds__(256) void k_norm_rope(const f16* __restrict__ qkv,
                                                   const int* __restrict__ pos_ids,
                                                   const float* __restrict__ qw,
                                                   const float* __restrict__ kw,
                                                   f16* __restrict__ Qo, f16* __restrict__ Ko) {
  int bt = blockIdx.x;
  int b = bt >> 11, t = bt & 2047;
  int tid = threadIdx.x, w = tid >> 6, lane = tid & 63;
  const f16* row = qkv + (size_t)bt * 3072;
  float pq = (float)pos_ids[t];
  float pk = (float)t;
  float inv = expf(-(float)lane * 0.14391156831212787f);
  for (int hi = w; hi < 20; hi += 4) {
    bool isq = hi < 16;
    int off = isq ? hi * 128 : 2048 + (hi - 16) * 128;
    float x1 = (float)row[off + 2 * lane];
    float x2 = (float)row[off + 2 * lane + 1];
    float ss = x1 * x1 + x2 * x2;
#pragma unroll
    for (int o = 1; o < 64; o <<= 1) ss += __shfl_xor(ss, o);
    float rms = rsqrtf(ss * (1.0f / 128.0f) + 1e-6f);
    const float* wt = isq ? qw : kw;
    float n1 = x1 * rms * wt[2 * lane], n2 = x2 * rms * wt[2 * lane + 1];
    float pos = isq ? pq : pk;
    float ang = pos * inv;
    float sn = sinf(ang), cs = cosf(ang);
    f16 r1 = (f16)(n1 * cs - n2 * sn), r2 = (f16)(n1 * sn + n2 * cs);
    if (isq) {
      f16* dst = Qo + (((size_t)b * HQ + hi) * TT + t) * HD;
      dst[2 * lane] = r1;
      dst[2 * lane + 1] = r2;
    } else {
      f16* dst = Ko + (((size_t)b * HKV + (hi - 16)) * TT + t) * HD;
      dst[2 * lane] = r1;
      dst[2 * lane + 1] = r2;
    }
  }
}

// ------- V transpose: from QKV buffer cols [2560..3072) -> Vt[b][hkv][d][t] -------
__global__ __launch_bounds__(256) void k_trV(const f16* __restrict__ qkv,
                                             f16* __restrict__ Vt) {
  __shared__ f16 tile[32][34];
  int t0 = blockIdx.x * 32, d0 = blockIdx.y * 32;
  int bh = blockIdx.z;
  int b = bh >> 2, hkv = bh & 3;
  int tx = threadIdx.x, ty = threadIdx.y;
  const f16* src = qkv + (size_t)b * 2048 * 3072 + 2560 + hkv * 128;
#pragma unroll
  for (int r = 0; r < 32; r += 8)
    tile[ty + r][tx] = src[(size_t)(t0 + ty + r) * 3072 + d0 + tx];
  __syncthreads();
  f16* dst = Vt + ((size_t)bh * HD + d0) * TT + t0;
#pragma unroll
  for (int r = 0; r < 32; r += 8)
    dst[(size_t)(ty + r) * TT + tx] = tile[tx][ty + r];
}

// ---- attention: 4 waves x 32q, 64-key tiles, swapped QK^T, gload_lds dbuf staging ----
__global__ __launch_bounds__(256, 2) void k_attn2(const f16* __restrict__ Q,
                                                  const f16* __restrict__ Kc,
                                                  const f16* __restrict__ Vt,
                                                  f16* __restrict__ Oa) {
  // double-buffered tiles; LDS linear, swizzle applied on GLOBAL source + on read
  __shared__ alignas(16) char KsC[2][64 * 256];   // K: 64 keys x 128 d (256B rows)
  __shared__ alignas(16) char VsC[2][128 * 128];  // V^T: 128 d x 64 keys (128B rows)
  int qt = blockIdx.x, h = blockIdx.y, b = blockIdx.z;
  int q0 = qt * 128, hkv = h >> 2;
  int tid = threadIdx.x;
  int w = tid >> 6, lane = tid & 63, ln = lane & 31, hi = lane >> 5;
  const char* KbB = (const char*)(Kc + ((size_t)b * HKV + hkv) * TT * HD);
  const char* VbB = (const char*)(Vt + ((size_t)b * HKV + hkv) * (size_t)HD * TT);
  int q = q0 + w * 32 + ln;
  const f16* Qp = Q + (((size_t)b * HQ + h) * TT + q) * HD + hi * 8;
  f16x8 qf[8];
#pragma unroll
  for (int st = 0; st < 8; st++) qf[st] = *(const f16x8*)&Qp[st * 16];
  f32x16 o[4] = {};
  float lsum = 0.f;
  int kfswz = (ln & 7) << 4;

  // staging source addressing (dest linear: byte = j*4096 + w*1024 + lane*16)
  int krow0 = w * 4 + (lane >> 4);                       // + j*16 per issue
  int kswzb = ((lane & 15) * 16) ^ ((krow0 & 7) << 4);   // pre-swizzled col byte
  int vrow0 = w * 8 + (lane >> 3);                       // + j*32 per issue
  int vswzb = ((lane & 7) * 16) ^ ((vrow0 & 7) << 4);

  int k0max = (q0 + 127) & ~63;
  int wlo = (q0 - 1023 > 128) ? ((q0 - 1023) & ~63) : 128;
  int nw = (k0max >= wlo) ? ((k0max - wlo) >> 6) + 1 : 0;
  int ntiles = 2 + nw;
  int qw = q0 + w * 32;

  const float C1 = 0.12751791217100872f;  // (1/sqrt(128)) * log2(e)
  const float C2 = 5.7707801635534255f;   // 4.0 * log2(e)  (fixed softmax shift)

  auto stage = [&](int buf, int k0) {
    const char* ks = KbB + (size_t)(k0 + krow0) * 256 + kswzb;
    const char* vs = VbB + (size_t)vrow0 * (TT * 2) + (size_t)k0 * 2 + vswzb;
    char* kd = KsC[buf] + w * 1024;
    char* vd = VsC[buf] + w * 1024;
#pragma unroll
    for (int j = 0; j < 4; j++) gload16(ks + (size_t)j * 4096, kd + j * 4096);
#pragma unroll
    for (int j = 0; j < 4; j++) gload16(vs + (size_t)j * 32 * (TT * 2), vd + j * 4096);
  };

  stage(0, 0);
  __syncthreads();
  int cur = 0;

  for (int ti = 0; ti < ntiles; ti++) {
    int k0 = (ti < 2) ? ti * 64 : wlo + (ti - 2) * 64;
    bool havenext = (ti + 1 < ntiles);
    if (havenext) {  // async loads for next tile; hidden under this tile's compute
      int k0n = (ti + 1 < 2) ? 64 : wlo + (ti - 1) * 64;
      stage(cur ^ 1, k0n);
    }
    bool needmask = false;
    if (ti >= 2) {
      int wsmax = qw + 31 - 1023;
      if (wsmax < 128) wsmax = 128;
      needmask = !((k0 + 63 <= qw) && (k0 >= wsmax));
    }
    f16x8 pa[2][2];
#pragma unroll
    for (int ksub = 0; ksub < 2; ksub++) {
      f32x16 s = {};
      const char* krow = KsC[cur] + (ksub * 32 + ln) * 256;
#pragma unroll
      for (int st = 0; st < 8; st++) {
        f16x8 kf = *(const f16x8*)(krow + ((st * 32 + hi * 16) ^ kfswz));
        s = MFMA32(kf, qf[st], s);  // S^T: lane col = q, regs = keys
      }
      int qmk = q - (k0 + ksub * 32 + 4 * hi);
      float pr[16];
#pragma unroll
      for (int r = 0; r < 16; r++) {
        float e = fast_exp2(s[r] * C1 - C2);
        if (needmask) {
          int kk = (r & 3) + 8 * (r >> 2);
          e = ((uint32_t)(qmk - kk) < 1024u) ? e : 0.0f;
        }
        lsum += e;
        pr[r] = e;
      }
      uint32_t c[8];
#pragma unroll
      for (int i = 0; i < 8; i++) c[i] = cvt_pk_u32(pr[2 * i], pr[2 * i + 1]);
      // Build PV A-fragments via shfl_xor(32) + per-lane select (validated r7).
      {
        uint32_t x0 = __shfl_xor(c[0], 32), x1 = __shfl_xor(c[1], 32);
        uint32_t x2 = __shfl_xor(c[2], 32), x3 = __shfl_xor(c[3], 32);
        u32x4 t0 = {hi ? x2 : c[0], hi ? x3 : c[1], hi ? c[2] : x0, hi ? c[3] : x1};
        pa[ksub][0] = __builtin_bit_cast(f16x8, t0);
        uint32_t x4 = __shfl_xor(c[4], 32), x5 = __shfl_xor(c[5], 32);
        uint32_t x6 = __shfl_xor(c[6], 32), x7 = __shfl_xor(c[7], 32);
        u32x4 t1 = {hi ? x6 : c[4], hi ? x7 : c[5], hi ? c[6] : x4, hi ? c[7] : x5};
        pa[ksub][1] = __builtin_bit_cast(f16x8, t1);
      }
    }
    // PV: o[q][d] += P[q][k] V[k][d]
#pragma unroll
    for (int dsub = 0; dsub < 4; dsub++) {
      const char* vrow = VsC[cur] + (dsub * 32 + ln) * 128;
#pragma unroll
      for (int ksub = 0; ksub < 2; ksub++)
#pragma unroll
        for (int st2 = 0; st2 < 2; st2++) {
          f16x8 vf = *(const f16x8*)(vrow + ((ksub * 64 + st2 * 32 + hi * 16) ^ kfswz));
          o[dsub] = MFMA32(pa[ksub][st2], vf, o[dsub]);
        }
    }
    __syncthreads();  // drains next-tile gload_lds (vmcnt) + all waves done with cur
    cur ^= 1;
  }
  // epilogue: finish l, scale, store
  lsum += __shfl_xor(lsum, 32);
  float rl[16];
#pragma unroll
  for (int r = 0; r < 16; r++) {
    int row = (r & 3) + 8 * (r >> 2) + 4 * hi;
    float lv = __shfl(lsum, row);
    rl[r] = 1.0f / lv;
  }
#pragma unroll
  for (int r = 0; r < 16; r++) {
    int row = (r & 3) + 8 * (r >> 2) + 4 * hi;
    size_t base = ((size_t)b * TT + q0 + w * 32 + row) * DM + (size_t)h * HD + ln;
#pragma unroll
    for (int dsub = 0; dsub < 4; dsub++)
      Oa[base + dsub * 32] = (f16)(o[dsub][r] * rl[r]);
  }
}

extern "C" void kernel_launch(void* const* d_in, const int* in_sizes, int n_in,
                              void* d_out, int out_size, void* d_ws, size_t ws_size,
                              hipStream_t stream) {
  const float* hidden = (const float*)d_in[0];
  const int* pos = (const int*)d_in[1];
  const float* Wq = (const float*)d_in[2];
  const float* Wk = (const float*)d_in[3];
  const float* Wv = (const float*)d_in[4];
  const float* Wo = (const float*)d_in[5];
  const float* qw = (const float*)d_in[6];
  const float* kw = (const float*)d_in[7];
  float* out = (float*)d_out;

  char* p = (char*)d_ws;
  auto take = [&](size_t n) {
    void* r = (void*)p;
    p += (n + 255) & ~(size_t)255;
    return r;
  };
  f16* Xb = (f16*)take((size_t)4096 * 2048 * 2);
  f16* WqkvT = (f16*)take((size_t)3072 * 2048 * 2);
  f16* WoT = (f16*)take((size_t)2048 * 2048 * 2);
  f16* QKVb = (f16*)take((size_t)4096 * 3072 * 2);
  f16* Qr = (f16*)take((size_t)BB * HQ * TT * HD * 2);
  f16* Kr = (f16*)take((size_t)BB * HKV * TT * HD * 2);
  f16* Vt = (f16*)take((size_t)BB * HKV * TT * HD * 2);
  f16* Attn = (f16*)take((size_t)4096 * 2048 * 2);

  dim3 tb(32, 8);
  k_cvt_f16<<<4096, 256, 0, stream>>>(hidden, Xb, 1048576);
  k_tr_cvt<<<dim3(64, 64), tb, 0, stream>>>(Wq, WqkvT, 2048, 2048);
  k_tr_cvt<<<dim3(16, 64), tb, 0, stream>>>(Wk, WqkvT + (size_t)2048 * 2048, 512, 2048);
  k_tr_cvt<<<dim3(16, 64), tb, 0, stream>>>(Wv, WqkvT + (size_t)2560 * 2048, 512, 2048);
  k_tr_cvt<<<dim3(64, 64), tb, 0, stream>>>(Wo, WoT, 2048, 2048);
  k_gemm<3072, true><<<768, 256, 0, stream>>>(Xb, WqkvT, QKVb, 4096, 2048);
  k_norm_rope<<<4096, 256, 0, stream>>>(QKVb, pos, qw, kw, Qr, Kr);
  k_trV<<<dim3(64, 4, 8), tb, 0, stream>>>(QKVb, Vt);
  k_attn2<<<dim3(16, 16, 2), 256, 0, stream>>>(Qr, Kr, Vt, Attn);
  k_gemm<2048, false><<<512, 256, 0, stream>>>(Attn, WoT, out, 4096, 2048);
}

// Round 9
// 224.146 us; speedup vs baseline: 1.2288x; 1.0918x over previous
//
#include <hip/hip_runtime.h>
#include <cstdint>
#include <cstddef>

#define DM 2048
#define TT 2048
#define BB 2
#define HQ 16
#define HKV 4
#define HD 128

typedef _Float16 f16;
using f16x8 = __attribute__((ext_vector_type(8))) f16;
using f32x4 = __attribute__((ext_vector_type(4))) float;
using f32x16 = __attribute__((ext_vector_type(16))) float;
using u32x4 = __attribute__((ext_vector_type(4))) uint32_t;

#define MFMA16(a, b, c) __builtin_amdgcn_mfma_f32_16x16x32_f16(a, b, c, 0, 0, 0)
#define MFMA32(a, b, c) __builtin_amdgcn_mfma_f32_32x32x16_f16(a, b, c, 0, 0, 0)

typedef __attribute__((address_space(1))) const void gvoid_t;
typedef __attribute__((address_space(3))) void lvoid_t;
static __device__ __forceinline__ void gload16(const void* g, void* l) {
  __builtin_amdgcn_global_load_lds((gvoid_t*)g, (lvoid_t*)l, 16, 0, 0);
}

static __device__ __forceinline__ float fast_exp2(float x) {
#if __has_builtin(__builtin_amdgcn_exp2f)
  return __builtin_amdgcn_exp2f(x);
#else
  return exp2f(x);
#endif
}

static __device__ __forceinline__ uint32_t cvt_pk_u32(float a, float b) {
  auto h2 = __builtin_amdgcn_cvt_pkrtz(a, b);
  return __builtin_bit_cast(uint32_t, h2);
}

// ---------------- fp32 -> fp16 convert (vectorized) ----------------
__global__ __launch_bounds__(256) void k_cvt_f16(const float* __restrict__ in,
                                                 f16* __restrict__ out, int n8) {
  int i = blockIdx.x * 256 + threadIdx.x;
  if (i >= n8) return;
  const float4* pin = (const float4*)in;
  float4 a = pin[2 * i], b = pin[2 * i + 1];
  f16x8 o = {(f16)a.x, (f16)a.y, (f16)a.z, (f16)a.w,
             (f16)b.x, (f16)b.y, (f16)b.z, (f16)b.w};
  *(f16x8*)&out[(size_t)8 * i] = o;
}

// ------------- transpose + convert: in fp32 [K][N] -> out f16 [N][K] -------------
__global__ __launch_bounds__(256) void k_tr_cvt(const float* __restrict__ in,
                                                f16* __restrict__ out, int N, int ldout) {
  __shared__ float tile[32][33];
  int n0 = blockIdx.x * 32, k0 = blockIdx.y * 32;
  int tx = threadIdx.x, ty = threadIdx.y;
#pragma unroll
  for (int r = 0; r < 32; r += 8) tile[ty + r][tx] = in[(size_t)(k0 + ty + r) * N + n0 + tx];
  __syncthreads();
#pragma unroll
  for (int r = 0; r < 32; r += 8)
    out[(size_t)(n0 + ty + r) * ldout + k0 + tx] = (f16)tile[tx][ty + r];
}

// ---- 8-phase 256x256 MFMA GEMM (T3+T4 counted staging, T2 swizzle, T5 setprio) ----
// C[M,N] = A[M,K] * BT[N,K]^T. 512 threads = 8 waves (2M x 4N), 128x64 out/wave.
template <int N_, bool OUT_F16>
__global__ __launch_bounds__(512, 2) void k_gemm8(const f16* __restrict__ A,
                                                  const f16* __restrict__ BT,
                                                  void* __restrict__ Cp, int M, int K) {
  __shared__ alignas(16) char Abuf[2][256 * 128];  // [buf] 256 rows x 128B, linear
  __shared__ alignas(16) char Bbuf[2][256 * 128];
  constexpr int NT = N_ / 256;
  int bid = blockIdx.x;
  int m0 = (bid / NT) * 256, n0 = (bid % NT) * 256;
  int tid = threadIdx.x;
  int lane = tid & 63, w = tid >> 6;
  int wr = w >> 2, wc = w & 3;
  int g = lane >> 4, c = lane & 15;
  int rswz = (c & 7) << 4;  // read-side XOR (row&7 == c&7 for all fragment rows)

  // staging: issue i covers rows 64i..64i+63; lane's source pre-swizzled so that
  // linear LDS[row][cb] == global[row][cb ^ ((row&7)<<4)]
  int srow = tid >> 3;                     // 0..63 within issue (row&7 == srow&7)
  int scbs = ((tid & 7) * 16) ^ ((srow & 7) << 4);
  const char* Ag = (const char*)A + (size_t)(m0 + srow) * (K * 2) + scbs;
  const char* Bg = (const char*)BT + (size_t)(n0 + srow) * (K * 2) + scbs;
  int lbase = w * 1024;  // wave-uniform LDS base; HW adds lane*16

  f32x4 acc[8][4] = {};
  int nk = K >> 6;

  auto stageA = [&](int buf, int kt, int i) {
    gload16(Ag + (size_t)(i * 64) * (K * 2) + (size_t)kt * 128,
            &Abuf[buf][i * 8192 + lbase]);
  };
  auto stageB = [&](int buf, int kt, int i) {
    gload16(Bg + (size_t)(i * 64) * (K * 2) + (size_t)kt * 128,
            &Bbuf[buf][i * 8192 + lbase]);
  };

  // prologue: stage K-tile 0 into buf 0, drain, publish
  {
#pragma unroll
    for (int i = 0; i < 4; i++) stageA(0, 0, i);
#pragma unroll
    for (int i = 0; i < 4; i++) stageB(0, 0, i);
    asm volatile("s_waitcnt vmcnt(0)" ::: "memory");
    __builtin_amdgcn_s_barrier();
  }

  for (int kt = 0; kt < nk; kt++) {
    int cur = kt & 1, nxt = cur ^ 1;
    bool more = (kt + 1) < nk;
    const char* Ab = Abuf[cur];
    const char* Bb = Bbuf[cur];
    f16x8 bf[4][2], af[2][2];
#pragma unroll
    for (int p = 0; p < 4; p++) {
      // ds-read subtile for this phase
      if (p == 0) {
#pragma unroll
        for (int nn = 0; nn < 4; nn++)
#pragma unroll
          for (int kk = 0; kk < 2; kk++) {
            int R = wc * 64 + nn * 16 + c;
            bf[nn][kk] = *(const f16x8*)(Bb + R * 128 + ((kk * 64 + g * 16) ^ rswz));
          }
      }
#pragma unroll
      for (int j = 0; j < 2; j++)
#pragma unroll
        for (int kk = 0; kk < 2; kk++) {
          int R = wr * 128 + (p * 2 + j) * 16 + c;
          af[j][kk] = *(const f16x8*)(Ab + R * 128 + ((kk * 64 + g * 16) ^ rswz));
        }
      // stage 2 half-tiles of K-tile kt+1 (loads stay in flight across barriers)
      if (more) {
        if (p == 0) { stageA(nxt, kt + 1, 0); stageA(nxt, kt + 1, 1); }
        else if (p == 1) { stageA(nxt, kt + 1, 2); stageA(nxt, kt + 1, 3); }
        else if (p == 2) { stageB(nxt, kt + 1, 0); stageB(nxt, kt + 1, 1); }
        else { stageB(nxt, kt + 1, 2); stageB(nxt, kt + 1, 3); }
      }
      __builtin_amdgcn_s_barrier();
      __builtin_amdgcn_s_setprio(1);
#pragma unroll
      for (int j = 0; j < 2; j++)
#pragma unroll
        for (int nn = 0; nn < 4; nn++)
#pragma unroll
          for (int kk = 0; kk < 2; kk++)
            acc[p * 2 + j][nn] = MFMA16(af[j][kk], bf[nn][kk], acc[p * 2 + j][nn]);
      __builtin_amdgcn_s_setprio(0);
      if (p == 3) asm volatile("s_waitcnt vmcnt(0)" ::: "memory");  // next tile landed
      __builtin_amdgcn_s_barrier();
    }
  }
  // epilogue: C-write
#pragma unroll
  for (int mm = 0; mm < 8; mm++)
#pragma unroll
    for (int nn = 0; nn < 4; nn++)
#pragma unroll
      for (int r = 0; r < 4; r++) {
        size_t row = m0 + wr * 128 + mm * 16 + g * 4 + r;
        size_t col = n0 + wc * 64 + nn * 16 + c;
        float v = acc[mm][nn][r];
        if constexpr (OUT_F16)
          ((f16*)Cp)[row * N_ + col] = (f16)v;
        else
          ((float*)Cp)[row * N_ + col] = v;
      }
}

// ---------------- RMSNorm + RoPE + relayout (Q, K only) ----------------
__global__ __launch_bounds__(256) void k_norm_rope(const f16* __restrict__ qkv,
                                                   const int* __restrict__ pos_ids,
                                                   const float* __restrict__ qw,
                                                   const float* __restrict__ kw,
                                                   f16* __restrict__ Qo, f16* __restrict__ Ko) {
  int bt = blockIdx.x;
  int b = bt >> 11, t = bt & 2047;
  int tid = threadIdx.x, w = tid >> 6, lane = tid & 63;
  const f16* row = qkv + (size_t)bt * 3072;
  float pq = (float)pos_ids[t];
  float pk = (float)t;
  float inv = expf(-(float)lane * 0.14391156831212787f);
  for (int hi = w; hi < 20; hi += 4) {
    bool isq = hi < 16;
    int off = isq ? hi * 128 : 2048 + (hi - 16) * 128;
    float x1 = (float)row[off + 2 * lane];
    float x2 = (float)row[off + 2 * lane + 1];
    float ss = x1 * x1 + x2 * x2;
#pragma unroll
    for (int o = 1; o < 64; o <<= 1) ss += __shfl_xor(ss, o);
    float rms = rsqrtf(ss * (1.0f / 128.0f) + 1e-6f);
    const float* wt = isq ? qw : kw;
    float n1 = x1 * rms * wt[2 * lane], n2 = x2 * rms * wt[2 * lane + 1];
    float pos = isq ? pq : pk;
    float ang = pos * inv;
    float sn = sinf(ang), cs = cosf(ang);
    f16 r1 = (f16)(n1 * cs - n2 * sn), r2 = (f16)(n1 * sn + n2 * cs);
    if (isq) {
      f16* dst = Qo + (((size_t)b * HQ + hi) * TT + t) * HD;
      dst[2 * lane] = r1;
      dst[2 * lane + 1] = r2;
    } else {
      f16* dst = Ko + (((size_t)b * HKV + (hi - 16)) * TT + t) * HD;
      dst[2 * lane] = r1;
      dst[2 * lane + 1] = r2;
    }
  }
}

// ------- V transpose: from QKV buffer cols [2560..3072) -> Vt[b][hkv][d][t] -------
__global__ __launch_bounds__(256) void k_trV(const f16* __restrict__ qkv,
                                             f16* __restrict__ Vt) {
  __shared__ f16 tile[32][34];
  int t0 = blockIdx.x * 32, d0 = blockIdx.y * 32;
  int bh = blockIdx.z;
  int b = bh >> 2, hkv = bh & 3;
  int tx = threadIdx.x, ty = threadIdx.y;
  const f16* src = qkv + (size_t)b * 2048 * 3072 + 2560 + hkv * 128;
#pragma unroll
  for (int r = 0; r < 32; r += 8)
    tile[ty + r][tx] = src[(size_t)(t0 + ty + r) * 3072 + d0 + tx];
  __syncthreads();
  f16* dst = Vt + ((size_t)bh * HD + d0) * TT + t0;
#pragma unroll
  for (int r = 0; r < 32; r += 8)
    dst[(size_t)(ty + r) * TT + tx] = tile[tx][ty + r];
}

// ---- attention: 4 waves x 32q, 64-key tiles, swapped QK^T, gload_lds dbuf staging ----
__global__ __launch_bounds__(256, 2) void k_attn2(const f16* __restrict__ Q,
                                                  const f16* __restrict__ Kc,
                                                  const f16* __restrict__ Vt,
                                                  f16* __restrict__ Oa) {
  // double-buffered tiles; LDS linear, swizzle applied on GLOBAL source + on read
  __shared__ alignas(16) char KsC[2][64 * 256];   // K: 64 keys x 128 d (256B rows)
  __shared__ alignas(16) char VsC[2][128 * 128];  // V^T: 128 d x 64 keys (128B rows)
  int qt = blockIdx.x, h = blockIdx.y, b = blockIdx.z;
  int q0 = qt * 128, hkv = h >> 2;
  int tid = threadIdx.x;
  int w = tid >> 6, lane = tid & 63, ln = lane & 31, hi = lane >> 5;
  const char* KbB = (const char*)(Kc + ((size_t)b * HKV + hkv) * TT * HD);
  const char* VbB = (const char*)(Vt + ((size_t)b * HKV + hkv) * (size_t)HD * TT);
  int q = q0 + w * 32 + ln;
  const f16* Qp = Q + (((size_t)b * HQ + h) * TT + q) * HD + hi * 8;
  f16x8 qf[8];
#pragma unroll
  for (int st = 0; st < 8; st++) qf[st] = *(const f16x8*)&Qp[st * 16];
  f32x16 o[4] = {};
  float lsum = 0.f;
  int kfswz = (ln & 7) << 4;

  // staging source addressing (dest linear: byte = j*4096 + w*1024 + lane*16)
  int krow0 = w * 4 + (lane >> 4);                       // + j*16 per issue
  int kswzb = ((lane & 15) * 16) ^ ((krow0 & 7) << 4);   // pre-swizzled col byte
  int vrow0 = w * 8 + (lane >> 3);                       // + j*32 per issue
  int vswzb = ((lane & 7) * 16) ^ ((vrow0 & 7) << 4);

  int k0max = (q0 + 127) & ~63;
  int wlo = (q0 - 1023 > 128) ? ((q0 - 1023) & ~63) : 128;
  int nw = (k0max >= wlo) ? ((k0max - wlo) >> 6) + 1 : 0;
  int ntiles = 2 + nw;
  int qw = q0 + w * 32;

  const float C1 = 0.12751791217100872f;  // (1/sqrt(128)) * log2(e)
  const float C2 = 5.7707801635534255f;   // 4.0 * log2(e)  (fixed softmax shift)

  auto stage = [&](int buf, int k0) {
    const char* ks = KbB + (size_t)(k0 + krow0) * 256 + kswzb;
    const char* vs = VbB + (size_t)vrow0 * (TT * 2) + (size_t)k0 * 2 + vswzb;
    char* kd = KsC[buf] + w * 1024;
    char* vd = VsC[buf] + w * 1024;
#pragma unroll
    for (int j = 0; j < 4; j++) gload16(ks + (size_t)j * 4096, kd + j * 4096);
#pragma unroll
    for (int j = 0; j < 4; j++) gload16(vs + (size_t)j * 32 * (TT * 2), vd + j * 4096);
  };

  stage(0, 0);
  __syncthreads();
  int cur = 0;

  for (int ti = 0; ti < ntiles; ti++) {
    int k0 = (ti < 2) ? ti * 64 : wlo + (ti - 2) * 64;
    bool havenext = (ti + 1 < ntiles);
    if (havenext) {  // async loads for next tile; hidden under this tile's compute
      int k0n = (ti + 1 < 2) ? 64 : wlo + (ti - 1) * 64;
      stage(cur ^ 1, k0n);
    }
    bool needmask = false;
    if (ti >= 2) {
      int wsmax = qw + 31 - 1023;
      if (wsmax < 128) wsmax = 128;
      needmask = !((k0 + 63 <= qw) && (k0 >= wsmax));
    }
    f16x8 pa[2][2];
#pragma unroll
    for (int ksub = 0; ksub < 2; ksub++) {
      f32x16 s = {};
      const char* krow = KsC[cur] + (ksub * 32 + ln) * 256;
#pragma unroll
      for (int st = 0; st < 8; st++) {
        f16x8 kf = *(const f16x8*)(krow + ((st * 32 + hi * 16) ^ kfswz));
        s = MFMA32(kf, qf[st], s);  // S^T: lane col = q, regs = keys
      }
      int qmk = q - (k0 + ksub * 32 + 4 * hi);
      float pr[16];
#pragma unroll
      for (int r = 0; r < 16; r++) {
        float e = fast_exp2(s[r] * C1 - C2);
        if (needmask) {
          int kk = (r & 3) + 8 * (r >> 2);
          e = ((uint32_t)(qmk - kk) < 1024u) ? e : 0.0f;
        }
        lsum += e;
        pr[r] = e;
      }
      uint32_t c[8];
#pragma unroll
      for (int i = 0; i < 8; i++) c[i] = cvt_pk_u32(pr[2 * i], pr[2 * i + 1]);
      // Build PV A-fragments via shfl_xor(32) + per-lane select (validated r7).
      {
        uint32_t x0 = __shfl_xor(c[0], 32), x1 = __shfl_xor(c[1], 32);
        uint32_t x2 = __shfl_xor(c[2], 32), x3 = __shfl_xor(c[3], 32);
        u32x4 t0 = {hi ? x2 : c[0], hi ? x3 : c[1], hi ? c[2] : x0, hi ? c[3] : x1};
        pa[ksub][0] = __builtin_bit_cast(f16x8, t0);
        uint32_t x4 = __shfl_xor(c[4], 32), x5 = __shfl_xor(c[5], 32);
        uint32_t x6 = __shfl_xor(c[6], 32), x7 = __shfl_xor(c[7], 32);
        u32x4 t1 = {hi ? x6 : c[4], hi ? x7 : c[5], hi ? c[6] : x4, hi ? c[7] : x5};
        pa[ksub][1] = __builtin_bit_cast(f16x8, t1);
      }
    }
    // PV: o[q][d] += P[q][k] V[k][d]
#pragma unroll
    for (int dsub = 0; dsub < 4; dsub++) {
      const char* vrow = VsC[cur] + (dsub * 32 + ln) * 128;
#pragma unroll
      for (int ksub = 0; ksub < 2; ksub++)
#pragma unroll
        for (int st2 = 0; st2 < 2; st2++) {
          f16x8 vf = *(const f16x8*)(vrow + ((ksub * 64 + st2 * 32 + hi * 16) ^ kfswz));
          o[dsub] = MFMA32(pa[ksub][st2], vf, o[dsub]);
        }
    }
    __syncthreads();  // drains next-tile gload_lds (vmcnt) + all waves done with cur
    cur ^= 1;
  }
  // epilogue: finish l, scale, store
  lsum += __shfl_xor(lsum, 32);
  float rl[16];
#pragma unroll
  for (int r = 0; r < 16; r++) {
    int row = (r & 3) + 8 * (r >> 2) + 4 * hi;
    float lv = __shfl(lsum, row);
    rl[r] = 1.0f / lv;
  }
#pragma unroll
  for (int r = 0; r < 16; r++) {
    int row = (r & 3) + 8 * (r >> 2) + 4 * hi;
    size_t base = ((size_t)b * TT + q0 + w * 32 + row) * DM + (size_t)h * HD + ln;
#pragma unroll
    for (int dsub = 0; dsub < 4; dsub++)
      Oa[base + dsub * 32] = (f16)(o[dsub][r] * rl[r]);
  }
}

extern "C" void kernel_launch(void* const* d_in, const int* in_sizes, int n_in,
                              void* d_out, int out_size, void* d_ws, size_t ws_size,
                              hipStream_t stream) {
  const float* hidden = (const float*)d_in[0];
  const int* pos = (const int*)d_in[1];
  const float* Wq = (const float*)d_in[2];
  const float* Wk = (const float*)d_in[3];
  const float* Wv = (const float*)d_in[4];
  const float* Wo = (const float*)d_in[5];
  const float* qw = (const float*)d_in[6];
  const float* kw = (const float*)d_in[7];
  float* out = (float*)d_out;

  char* p = (char*)d_ws;
  auto take = [&](size_t n) {
    void* r = (void*)p;
    p += (n + 255) & ~(size_t)255;
    return r;
  };
  f16* Xb = (f16*)take((size_t)4096 * 2048 * 2);
  f16* WqkvT = (f16*)take((size_t)3072 * 2048 * 2);
  f16* WoT = (f16*)take((size_t)2048 * 2048 * 2);
  f16* QKVb = (f16*)take((size_t)4096 * 3072 * 2);
  f16* Qr = (f16*)take((size_t)BB * HQ * TT * HD * 2);
  f16* Kr = (f16*)take((size_t)BB * HKV * TT * HD * 2);
  f16* Vt = (f16*)take((size_t)BB * HKV * TT * HD * 2);
  f16* Attn = (f16*)take((size_t)4096 * 2048 * 2);

  dim3 tb(32, 8);
  k_cvt_f16<<<4096, 256, 0, stream>>>(hidden, Xb, 1048576);
  k_tr_cvt<<<dim3(64, 64), tb, 0, stream>>>(Wq, WqkvT, 2048, 2048);
  k_tr_cvt<<<dim3(16, 64), tb, 0, stream>>>(Wk, WqkvT + (size_t)2048 * 2048, 512, 2048);
  k_tr_cvt<<<dim3(16, 64), tb, 0, stream>>>(Wv, WqkvT + (size_t)2560 * 2048, 512, 2048);
  k_tr_cvt<<<dim3(64, 64), tb, 0, stream>>>(Wo, WoT, 2048, 2048);
  k_gemm8<3072, true><<<192, 512, 0, stream>>>(Xb, WqkvT, QKVb, 4096, 2048);
  k_norm_rope<<<4096, 256, 0, stream>>>(QKVb, pos, qw, kw, Qr, Kr);
  k_trV<<<dim3(64, 4, 8), tb, 0, stream>>>(QKVb, Vt);
  k_attn2<<<dim3(16, 16, 2), 256, 0, stream>>>(Qr, Kr, Vt, Attn);
  k_gemm8<2048, false><<<128, 512, 0, stream>>>(Attn, WoT, out, 4096, 2048);
}

// Round 10
// 207.656 us; speedup vs baseline: 1.3264x; 1.0794x over previous
//
#include <hip/hip_runtime.h>
#include <cstdint>
#include <cstddef>

#define DM 2048
#define TT 2048
#define BB 2
#define HQ 16
#define HKV 4
#define HD 128

typedef _Float16 f16;
using f16x8 = __attribute__((ext_vector_type(8))) f16;
using f32x4 = __attribute__((ext_vector_type(4))) float;
using f32x16 = __attribute__((ext_vector_type(16))) float;
using u32x4 = __attribute__((ext_vector_type(4))) uint32_t;

#define MFMA16(a, b, c) __builtin_amdgcn_mfma_f32_16x16x32_f16(a, b, c, 0, 0, 0)
#define MFMA32(a, b, c) __builtin_amdgcn_mfma_f32_32x32x16_f16(a, b, c, 0, 0, 0)

typedef __attribute__((address_space(1))) const void gvoid_t;
typedef __attribute__((address_space(3))) void lvoid_t;
static __device__ __forceinline__ void gload16(const void* g, void* l) {
  __builtin_amdgcn_global_load_lds((gvoid_t*)g, (lvoid_t*)l, 16, 0, 0);
}

static __device__ __forceinline__ float fast_exp2(float x) {
#if __has_builtin(__builtin_amdgcn_exp2f)
  return __builtin_amdgcn_exp2f(x);
#else
  return exp2f(x);
#endif
}

static __device__ __forceinline__ uint32_t cvt_pk_u32(float a, float b) {
  auto h2 = __builtin_amdgcn_cvt_pkrtz(a, b);
  return __builtin_bit_cast(uint32_t, h2);
}

// ---------------- fp32 -> fp16 convert (vectorized) ----------------
__global__ __launch_bounds__(256) void k_cvt_f16(const float* __restrict__ in,
                                                 f16* __restrict__ out, int n8) {
  int i = blockIdx.x * 256 + threadIdx.x;
  if (i >= n8) return;
  const float4* pin = (const float4*)in;
  float4 a = pin[2 * i], b = pin[2 * i + 1];
  f16x8 o = {(f16)a.x, (f16)a.y, (f16)a.z, (f16)a.w,
             (f16)b.x, (f16)b.y, (f16)b.z, (f16)b.w};
  *(f16x8*)&out[(size_t)8 * i] = o;
}

// ------------- transpose + convert: in fp32 [K][N] -> out f16 [N][K] -------------
__global__ __launch_bounds__(256) void k_tr_cvt(const float* __restrict__ in,
                                                f16* __restrict__ out, int N, int ldout) {
  __shared__ float tile[32][33];
  int n0 = blockIdx.x * 32, k0 = blockIdx.y * 32;
  int tx = threadIdx.x, ty = threadIdx.y;
#pragma unroll
  for (int r = 0; r < 32; r += 8) tile[ty + r][tx] = in[(size_t)(k0 + ty + r) * N + n0 + tx];
  __syncthreads();
#pragma unroll
  for (int r = 0; r < 32; r += 8)
    out[(size_t)(n0 + ty + r) * ldout + k0 + tx] = (f16)tile[tx][ty + r];
}

// ---- 8-phase 256xBN MFMA GEMM (T3+T4 counted staging, T2 swizzle, T5 setprio) ----
// C[M,N] = A[M,K] * BT[N,K]^T. 512 threads = 8 waves (2M x 4N), 128 x BN/4 out/wave.
template <int BN_, int N_, bool OUT_F16>
__global__ __launch_bounds__(512, 2) void k_gemm8(const f16* __restrict__ A,
                                                  const f16* __restrict__ BT,
                                                  void* __restrict__ Cp, int M, int K) {
  constexpr int NF = BN_ / 64;   // 16-col B-fragments per wave
  constexpr int BI = BN_ / 64;   // B staging issues (64 rows each)
  __shared__ alignas(16) char Abuf[2][256 * 128];  // 256 rows x 128B, linear
  __shared__ alignas(16) char Bbuf[2][BN_ * 128];
  constexpr int NT = N_ / BN_;
  int bid = blockIdx.x;
  int m0 = (bid / NT) * 256, n0 = (bid % NT) * BN_;
  int tid = threadIdx.x;
  int lane = tid & 63, w = tid >> 6;
  int wr = w >> 2, wc = w & 3;
  int g = lane >> 4, c = lane & 15;
  int rswz = (c & 7) << 4;  // read-side XOR (fragment row&7 == c&7)

  // staging: issue i covers rows 64i..64i+63; source pre-swizzled so that
  // linear LDS[row][cb] == global[row][cb ^ ((row&7)<<4)]
  int srow = tid >> 3;                     // 0..63 within issue
  int scbs = ((tid & 7) * 16) ^ ((srow & 7) << 4);
  const char* Ag = (const char*)A + (size_t)(m0 + srow) * (K * 2) + scbs;
  const char* Bg = (const char*)BT + (size_t)(n0 + srow) * (K * 2) + scbs;
  int lbase = w * 1024;  // wave-uniform LDS base; HW adds lane*16

  f32x4 acc[8][NF] = {};
  int nk = K >> 6;

  auto stageA = [&](int buf, int kt, int i) {
    gload16(Ag + (size_t)(i * 64) * (K * 2) + (size_t)kt * 128,
            &Abuf[buf][i * 8192 + lbase]);
  };
  auto stageB = [&](int buf, int kt, int i) {
    gload16(Bg + (size_t)(i * 64) * (K * 2) + (size_t)kt * 128,
            &Bbuf[buf][i * 8192 + lbase]);
  };

  // prologue: stage K-tile 0 into buf 0, drain, publish
  {
#pragma unroll
    for (int i = 0; i < 4; i++) stageA(0, 0, i);
#pragma unroll
    for (int i = 0; i < BI; i++) stageB(0, 0, i);
    asm volatile("s_waitcnt vmcnt(0)" ::: "memory");
    __builtin_amdgcn_s_barrier();
  }

  for (int kt = 0; kt < nk; kt++) {
    int cur = kt & 1, nxt = cur ^ 1;
    bool more = (kt + 1) < nk;
    const char* Ab = Abuf[cur];
    const char* Bb = Bbuf[cur];
    f16x8 bf[NF][2], af[2][2];
#pragma unroll
    for (int p = 0; p < 4; p++) {
      if (p == 0) {
#pragma unroll
        for (int nn = 0; nn < NF; nn++)
#pragma unroll
          for (int kk = 0; kk < 2; kk++) {
            int R = wc * (NF * 16) + nn * 16 + c;
            bf[nn][kk] = *(const f16x8*)(Bb + R * 128 + ((kk * 64 + g * 16) ^ rswz));
          }
      }
#pragma unroll
      for (int j = 0; j < 2; j++)
#pragma unroll
        for (int kk = 0; kk < 2; kk++) {
          int R = wr * 128 + (p * 2 + j) * 16 + c;
          af[j][kk] = *(const f16x8*)(Ab + R * 128 + ((kk * 64 + g * 16) ^ rswz));
        }
      // issue-early: all next-tile loads go out in phases 0-1 (max slack to drain)
      if (more) {
        if (p == 0) {
          stageA(nxt, kt + 1, 0); stageA(nxt, kt + 1, 1); stageB(nxt, kt + 1, 0);
        } else if (p == 1) {
          stageA(nxt, kt + 1, 2); stageA(nxt, kt + 1, 3); stageB(nxt, kt + 1, 1);
          if constexpr (BI == 3) stageB(nxt, kt + 1, 2);
        }
      }
      __builtin_amdgcn_s_barrier();
      __builtin_amdgcn_s_setprio(1);
#pragma unroll
      for (int j = 0; j < 2; j++)
#pragma unroll
        for (int nn = 0; nn < NF; nn++)
#pragma unroll
          for (int kk = 0; kk < 2; kk++)
            acc[p * 2 + j][nn] = MFMA16(af[j][kk], bf[nn][kk], acc[p * 2 + j][nn]);
      __builtin_amdgcn_s_setprio(0);
      if (p == 3) asm volatile("s_waitcnt vmcnt(0)" ::: "memory");  // next tile landed
      __builtin_amdgcn_s_barrier();
    }
  }
  // epilogue: C-write
#pragma unroll
  for (int mm = 0; mm < 8; mm++)
#pragma unroll
    for (int nn = 0; nn < NF; nn++)
#pragma unroll
      for (int r = 0; r < 4; r++) {
        size_t row = m0 + wr * 128 + mm * 16 + g * 4 + r;
        size_t col = n0 + wc * (NF * 16) + nn * 16 + c;
        float v = acc[mm][nn][r];
        if constexpr (OUT_F16)
          ((f16*)Cp)[row * N_ + col] = (f16)v;
        else
          ((float*)Cp)[row * N_ + col] = v;
      }
}

// ---------------- RMSNorm + RoPE + relayout (Q, K only) ----------------
__global__ __launch_bounds__(256) void k_norm_rope(const f16* __restrict__ qkv,
                                                   const int* __restrict__ pos_ids,
                                                   const float* __restrict__ qw,
                                                   const float* __restrict__ kw,
                                                   f16* __restrict__ Qo, f16* __restrict__ Ko) {
  int bt = blockIdx.x;
  int b = bt >> 11, t = bt & 2047;
  int tid = threadIdx.x, w = tid >> 6, lane = tid & 63;
  const f16* row = qkv + (size_t)bt * 3072;
  float pq = (float)pos_ids[t];
  float pk = (float)t;
  float inv = expf(-(float)lane * 0.14391156831212787f);
  for (int hi = w; hi < 20; hi += 4) {
    bool isq = hi < 16;
    int off = isq ? hi * 128 : 2048 + (hi - 16) * 128;
    float x1 = (float)row[off + 2 * lane];
    float x2 = (float)row[off + 2 * lane + 1];
    float ss = x1 * x1 + x2 * x2;
#pragma unroll
    for (int o = 1; o < 64; o <<= 1) ss += __shfl_xor(ss, o);
    float rms = rsqrtf(ss * (1.0f / 128.0f) + 1e-6f);
    const float* wt = isq ? qw : kw;
    float n1 = x1 * rms * wt[2 * lane], n2 = x2 * rms * wt[2 * lane + 1];
    float pos = isq ? pq : pk;
    float ang = pos * inv;
    float sn = sinf(ang), cs = cosf(ang);
    f16 r1 = (f16)(n1 * cs - n2 * sn), r2 = (f16)(n1 * sn + n2 * cs);
    if (isq) {
      f16* dst = Qo + (((size_t)b * HQ + hi) * TT + t) * HD;
      dst[2 * lane] = r1;
      dst[2 * lane + 1] = r2;
    } else {
      f16* dst = Ko + (((size_t)b * HKV + (hi - 16)) * TT + t) * HD;
      dst[2 * lane] = r1;
      dst[2 * lane + 1] = r2;
    }
  }
}

// ------- V transpose: from QKV buffer cols [2560..3072) -> Vt[b][hkv][d][t] -------
__global__ __launch_bounds__(256) void k_trV(const f16* __restrict__ qkv,
                                             f16* __restrict__ Vt) {
  __shared__ f16 tile[32][34];
  int t0 = blockIdx.x * 32, d0 = blockIdx.y * 32;
  int bh = blockIdx.z;
  int b = bh >> 2, hkv = bh & 3;
  int tx = threadIdx.x, ty = threadIdx.y;
  const f16* src = qkv + (size_t)b * 2048 * 3072 + 2560 + hkv * 128;
#pragma unroll
  for (int r = 0; r < 32; r += 8)
    tile[ty + r][tx] = src[(size_t)(t0 + ty + r) * 3072 + d0 + tx];
  __syncthreads();
  f16* dst = Vt + ((size_t)bh * HD + d0) * TT + t0;
#pragma unroll
  for (int r = 0; r < 32; r += 8)
    dst[(size_t)(ty + r) * TT + tx] = tile[tx][ty + r];
}

// ---- attention: 4 waves x 32q, 64-key tiles, swapped QK^T, gload_lds dbuf staging ----
__global__ __launch_bounds__(256, 2) void k_attn2(const f16* __restrict__ Q,
                                                  const f16* __restrict__ Kc,
                                                  const f16* __restrict__ Vt,
                                                  f16* __restrict__ Oa) {
  // double-buffered tiles; LDS linear, swizzle applied on GLOBAL source + on read
  __shared__ alignas(16) char KsC[2][64 * 256];   // K: 64 keys x 128 d (256B rows)
  __shared__ alignas(16) char VsC[2][128 * 128];  // V^T: 128 d x 64 keys (128B rows)
  int qt = blockIdx.x, h = blockIdx.y, b = blockIdx.z;
  int q0 = qt * 128, hkv = h >> 2;
  int tid = threadIdx.x;
  int w = tid >> 6, lane = tid & 63, ln = lane & 31, hi = lane >> 5;
  const char* KbB = (const char*)(Kc + ((size_t)b * HKV + hkv) * TT * HD);
  const char* VbB = (const char*)(Vt + ((size_t)b * HKV + hkv) * (size_t)HD * TT);
  int q = q0 + w * 32 + ln;
  const f16* Qp = Q + (((size_t)b * HQ + h) * TT + q) * HD + hi * 8;
  f16x8 qf[8];
#pragma unroll
  for (int st = 0; st < 8; st++) qf[st] = *(const f16x8*)&Qp[st * 16];
  f32x16 o[4] = {};
  float lsum = 0.f;
  int kfswz = (ln & 7) << 4;

  // staging source addressing (dest linear: byte = j*4096 + w*1024 + lane*16)
  int krow0 = w * 4 + (lane >> 4);                       // + j*16 per issue
  int kswzb = ((lane & 15) * 16) ^ ((krow0 & 7) << 4);   // pre-swizzled col byte
  int vrow0 = w * 8 + (lane >> 3);                       // + j*32 per issue
  int vswzb = ((lane & 7) * 16) ^ ((vrow0 & 7) << 4);

  int k0max = (q0 + 127) & ~63;
  int wlo = (q0 - 1023 > 128) ? ((q0 - 1023) & ~63) : 128;
  int nw = (k0max >= wlo) ? ((k0max - wlo) >> 6) + 1 : 0;
  int ntiles = 2 + nw;
  int qw = q0 + w * 32;

  const float C1 = 0.12751791217100872f;  // (1/sqrt(128)) * log2(e)
  const float C2 = 5.7707801635534255f;   // 4.0 * log2(e)  (fixed softmax shift)

  auto stage = [&](int buf, int k0) {
    const char* ks = KbB + (size_t)(k0 + krow0) * 256 + kswzb;
    const char* vs = VbB + (size_t)vrow0 * (TT * 2) + (size_t)k0 * 2 + vswzb;
    char* kd = KsC[buf] + w * 1024;
    char* vd = VsC[buf] + w * 1024;
#pragma unroll
    for (int j = 0; j < 4; j++) gload16(ks + (size_t)j * 4096, kd + j * 4096);
#pragma unroll
    for (int j = 0; j < 4; j++) gload16(vs + (size_t)j * 32 * (TT * 2), vd + j * 4096);
  };

  stage(0, 0);
  __syncthreads();
  int cur = 0;

  for (int ti = 0; ti < ntiles; ti++) {
    int k0 = (ti < 2) ? ti * 64 : wlo + (ti - 2) * 64;
    bool havenext = (ti + 1 < ntiles);
    if (havenext) {  // async loads for next tile; hidden under this tile's compute
      int k0n = (ti + 1 < 2) ? 64 : wlo + (ti - 1) * 64;
      stage(cur ^ 1, k0n);
    }
    bool needmask = false;
    if (ti >= 2) {
      int wsmax = qw + 31 - 1023;
      if (wsmax < 128) wsmax = 128;
      needmask = !((k0 + 63 <= qw) && (k0 >= wsmax));
    }
    f16x8 pa[2][2];
#pragma unroll
    for (int ksub = 0; ksub < 2; ksub++) {
      f32x16 s = {};
      const char* krow = KsC[cur] + (ksub * 32 + ln) * 256;
#pragma unroll
      for (int st = 0; st < 8; st++) {
        f16x8 kf = *(const f16x8*)(krow + ((st * 32 + hi * 16) ^ kfswz));
        s = MFMA32(kf, qf[st], s);  // S^T: lane col = q, regs = keys
      }
      int qmk = q - (k0 + ksub * 32 + 4 * hi);
      float pr[16];
#pragma unroll
      for (int r = 0; r < 16; r++) {
        float e = fast_exp2(s[r] * C1 - C2);
        if (needmask) {
          int kk = (r & 3) + 8 * (r >> 2);
          e = ((uint32_t)(qmk - kk) < 1024u) ? e : 0.0f;
        }
        lsum += e;
        pr[r] = e;
      }
      uint32_t c[8];
#pragma unroll
      for (int i = 0; i < 8; i++) c[i] = cvt_pk_u32(pr[2 * i], pr[2 * i + 1]);
      // Build PV A-fragments via shfl_xor(32) + per-lane select (validated r7).
      {
        uint32_t x0 = __shfl_xor(c[0], 32), x1 = __shfl_xor(c[1], 32);
        uint32_t x2 = __shfl_xor(c[2], 32), x3 = __shfl_xor(c[3], 32);
        u32x4 t0 = {hi ? x2 : c[0], hi ? x3 : c[1], hi ? c[2] : x0, hi ? c[3] : x1};
        pa[ksub][0] = __builtin_bit_cast(f16x8, t0);
        uint32_t x4 = __shfl_xor(c[4], 32), x5 = __shfl_xor(c[5], 32);
        uint32_t x6 = __shfl_xor(c[6], 32), x7 = __shfl_xor(c[7], 32);
        u32x4 t1 = {hi ? x6 : c[4], hi ? x7 : c[5], hi ? c[6] : x4, hi ? c[7] : x5};
        pa[ksub][1] = __builtin_bit_cast(f16x8, t1);
      }
    }
    // PV: o[q][d] += P[q][k] V[k][d]
#pragma unroll
    for (int dsub = 0; dsub < 4; dsub++) {
      const char* vrow = VsC[cur] + (dsub * 32 + ln) * 128;
#pragma unroll
      for (int ksub = 0; ksub < 2; ksub++)
#pragma unroll
        for (int st2 = 0; st2 < 2; st2++) {
          f16x8 vf = *(const f16x8*)(vrow + ((ksub * 64 + st2 * 32 + hi * 16) ^ kfswz));
          o[dsub] = MFMA32(pa[ksub][st2], vf, o[dsub]);
        }
    }
    __syncthreads();  // drains next-tile gload_lds (vmcnt) + all waves done with cur
    cur ^= 1;
  }
  // epilogue: finish l, scale, store
  lsum += __shfl_xor(lsum, 32);
  float rl[16];
#pragma unroll
  for (int r = 0; r < 16; r++) {
    int row = (r & 3) + 8 * (r >> 2) + 4 * hi;
    float lv = __shfl(lsum, row);
    rl[r] = 1.0f / lv;
  }
#pragma unroll
  for (int r = 0; r < 16; r++) {
    int row = (r & 3) + 8 * (r >> 2) + 4 * hi;
    size_t base = ((size_t)b * TT + q0 + w * 32 + row) * DM + (size_t)h * HD + ln;
#pragma unroll
    for (int dsub = 0; dsub < 4; dsub++)
      Oa[base + dsub * 32] = (f16)(o[dsub][r] * rl[r]);
  }
}

extern "C" void kernel_launch(void* const* d_in, const int* in_sizes, int n_in,
                              void* d_out, int out_size, void* d_ws, size_t ws_size,
                              hipStream_t stream) {
  const float* hidden = (const float*)d_in[0];
  const int* pos = (const int*)d_in[1];
  const float* Wq = (const float*)d_in[2];
  const float* Wk = (const float*)d_in[3];
  const float* Wv = (const float*)d_in[4];
  const float* Wo = (const float*)d_in[5];
  const float* qw = (const float*)d_in[6];
  const float* kw = (const float*)d_in[7];
  float* out = (float*)d_out;

  char* p = (char*)d_ws;
  auto take = [&](size_t n) {
    void* r = (void*)p;
    p += (n + 255) & ~(size_t)255;
    return r;
  };
  f16* Xb = (f16*)take((size_t)4096 * 2048 * 2);
  f16* WqkvT = (f16*)take((size_t)3072 * 2048 * 2);
  f16* WoT = (f16*)take((size_t)2048 * 2048 * 2);
  f16* QKVb = (f16*)take((size_t)4096 * 3072 * 2);
  f16* Qr = (f16*)take((size_t)BB * HQ * TT * HD * 2);
  f16* Kr = (f16*)take((size_t)BB * HKV * TT * HD * 2);
  f16* Vt = (f16*)take((size_t)BB * HKV * TT * HD * 2);
  f16* Attn = (f16*)take((size_t)4096 * 2048 * 2);

  dim3 tb(32, 8);
  k_cvt_f16<<<4096, 256, 0, stream>>>(hidden, Xb, 1048576);
  k_tr_cvt<<<dim3(64, 64), tb, 0, stream>>>(Wq, WqkvT, 2048, 2048);
  k_tr_cvt<<<dim3(16, 64), tb, 0, stream>>>(Wk, WqkvT + (size_t)2048 * 2048, 512, 2048);
  k_tr_cvt<<<dim3(16, 64), tb, 0, stream>>>(Wv, WqkvT + (size_t)2560 * 2048, 512, 2048);
  k_tr_cvt<<<dim3(64, 64), tb, 0, stream>>>(Wo, WoT, 2048, 2048);
  k_gemm8<192, 3072, true><<<256, 512, 0, stream>>>(Xb, WqkvT, QKVb, 4096, 2048);
  k_norm_rope<<<4096, 256, 0, stream>>>(QKVb, pos, qw, kw, Qr, Kr);
  k_trV<<<dim3(64, 4, 8), tb, 0, stream>>>(QKVb, Vt);
  k_attn2<<<dim3(16, 16, 2), 256, 0, stream>>>(Qr, Kr, Vt, Attn);
  k_gemm8<128, 2048, false><<<256, 512, 0, stream>>>(Attn, WoT, out, 4096, 2048);
}

// Round 11
// 204.132 us; speedup vs baseline: 1.3493x; 1.0173x over previous
//
#include <hip/hip_runtime.h>
#include <cstdint>
#include <cstddef>

#define DM 2048
#define TT 2048
#define BB 2
#define HQ 16
#define HKV 4
#define HD 128

typedef _Float16 f16;
using f16x8 = __attribute__((ext_vector_type(8))) f16;
using f32x4 = __attribute__((ext_vector_type(4))) float;
using f32x16 = __attribute__((ext_vector_type(16))) float;
using u32x4 = __attribute__((ext_vector_type(4))) uint32_t;

#define MFMA16(a, b, c) __builtin_amdgcn_mfma_f32_16x16x32_f16(a, b, c, 0, 0, 0)
#define MFMA32(a, b, c) __builtin_amdgcn_mfma_f32_32x32x16_f16(a, b, c, 0, 0, 0)

typedef __attribute__((address_space(1))) const void gvoid_t;
typedef __attribute__((address_space(3))) void lvoid_t;
static __device__ __forceinline__ void gload16(const void* g, void* l) {
  __builtin_amdgcn_global_load_lds((gvoid_t*)g, (lvoid_t*)l, 16, 0, 0);
}

static __device__ __forceinline__ float fast_exp2(float x) {
#if __has_builtin(__builtin_amdgcn_exp2f)
  return __builtin_amdgcn_exp2f(x);
#else
  return exp2f(x);
#endif
}

static __device__ __forceinline__ uint32_t cvt_pk_u32(float a, float b) {
  auto h2 = __builtin_amdgcn_cvt_pkrtz(a, b);
  return __builtin_bit_cast(uint32_t, h2);
}

// ---------------- fp32 -> fp16 convert (vectorized) ----------------
__global__ __launch_bounds__(256) void k_cvt_f16(const float* __restrict__ in,
                                                 f16* __restrict__ out, int n8) {
  int i = blockIdx.x * 256 + threadIdx.x;
  if (i >= n8) return;
  const float4* pin = (const float4*)in;
  float4 a = pin[2 * i], b = pin[2 * i + 1];
  f16x8 o = {(f16)a.x, (f16)a.y, (f16)a.z, (f16)a.w,
             (f16)b.x, (f16)b.y, (f16)b.z, (f16)b.w};
  *(f16x8*)&out[(size_t)8 * i] = o;
}

// ------------- transpose + convert: in fp32 [K][N] -> out f16 [N][K] -------------
__global__ __launch_bounds__(256) void k_tr_cvt(const float* __restrict__ in,
                                                f16* __restrict__ out, int N, int ldout) {
  __shared__ float tile[32][33];
  int n0 = blockIdx.x * 32, k0 = blockIdx.y * 32;
  int tx = threadIdx.x, ty = threadIdx.y;
#pragma unroll
  for (int r = 0; r < 32; r += 8) tile[ty + r][tx] = in[(size_t)(k0 + ty + r) * N + n0 + tx];
  __syncthreads();
#pragma unroll
  for (int r = 0; r < 32; r += 8)
    out[(size_t)(n0 + ty + r) * ldout + k0 + tx] = (f16)tile[tx][ty + r];
}

// ---- 8-phase 256xBN MFMA GEMM (T3+T4 counted staging, T2 swizzle, T5 setprio) ----
// C[M,N] = A[M,K] * BT[N,K]^T. 512 threads = 8 waves (2M x 4N), 128 x BN/4 out/wave.
template <int BN_, int N_, bool OUT_F16>
__global__ __launch_bounds__(512, 2) void k_gemm8(const f16* __restrict__ A,
                                                  const f16* __restrict__ BT,
                                                  void* __restrict__ Cp, int M, int K) {
  constexpr int NF = BN_ / 64;   // 16-col B-fragments per wave
  constexpr int BI = BN_ / 64;   // B staging issues (64 rows each)
  __shared__ alignas(16) char Abuf[2][256 * 128];  // 256 rows x 128B, linear
  __shared__ alignas(16) char Bbuf[2][BN_ * 128];
  constexpr int NT = N_ / BN_;
  int bid = blockIdx.x;
  int m0 = (bid / NT) * 256, n0 = (bid % NT) * BN_;
  int tid = threadIdx.x;
  int lane = tid & 63, w = tid >> 6;
  int wr = w >> 2, wc = w & 3;
  int g = lane >> 4, c = lane & 15;
  int rswz = (c & 7) << 4;  // read-side XOR (fragment row&7 == c&7)

  // staging: issue i covers rows 64i..64i+63; source pre-swizzled so that
  // linear LDS[row][cb] == global[row][cb ^ ((row&7)<<4)]
  int srow = tid >> 3;                     // 0..63 within issue
  int scbs = ((tid & 7) * 16) ^ ((srow & 7) << 4);
  const char* Ag = (const char*)A + (size_t)(m0 + srow) * (K * 2) + scbs;
  const char* Bg = (const char*)BT + (size_t)(n0 + srow) * (K * 2) + scbs;
  int lbase = w * 1024;  // wave-uniform LDS base; HW adds lane*16

  f32x4 acc[8][NF] = {};
  int nk = K >> 6;

  auto stageA = [&](int buf, int kt, int i) {
    gload16(Ag + (size_t)(i * 64) * (K * 2) + (size_t)kt * 128,
            &Abuf[buf][i * 8192 + lbase]);
  };
  auto stageB = [&](int buf, int kt, int i) {
    gload16(Bg + (size_t)(i * 64) * (K * 2) + (size_t)kt * 128,
            &Bbuf[buf][i * 8192 + lbase]);
  };

  // prologue: stage K-tile 0 into buf 0, drain, publish
  {
#pragma unroll
    for (int i = 0; i < 4; i++) stageA(0, 0, i);
#pragma unroll
    for (int i = 0; i < BI; i++) stageB(0, 0, i);
    asm volatile("s_waitcnt vmcnt(0)" ::: "memory");
    __builtin_amdgcn_s_barrier();
  }

  for (int kt = 0; kt < nk; kt++) {
    int cur = kt & 1, nxt = cur ^ 1;
    bool more = (kt + 1) < nk;
    const char* Ab = Abuf[cur];
    const char* Bb = Bbuf[cur];
    f16x8 bf[NF][2], af[2][2];
#pragma unroll
    for (int p = 0; p < 4; p++) {
      if (p == 0) {
#pragma unroll
        for (int nn = 0; nn < NF; nn++)
#pragma unroll
          for (int kk = 0; kk < 2; kk++) {
            int R = wc * (NF * 16) + nn * 16 + c;
            bf[nn][kk] = *(const f16x8*)(Bb + R * 128 + ((kk * 64 + g * 16) ^ rswz));
          }
      }
#pragma unroll
      for (int j = 0; j < 2; j++)
#pragma unroll
        for (int kk = 0; kk < 2; kk++) {
          int R = wr * 128 + (p * 2 + j) * 16 + c;
          af[j][kk] = *(const f16x8*)(Ab + R * 128 + ((kk * 64 + g * 16) ^ rswz));
        }
      // issue-early: all next-tile loads go out in phases 0-1 (max slack to drain)
      if (more) {
        if (p == 0) {
          stageA(nxt, kt + 1, 0); stageA(nxt, kt + 1, 1); stageB(nxt, kt + 1, 0);
        } else if (p == 1) {
          stageA(nxt, kt + 1, 2); stageA(nxt, kt + 1, 3); stageB(nxt, kt + 1, 1);
          if constexpr (BI == 3) stageB(nxt, kt + 1, 2);
        }
      }
      __builtin_amdgcn_s_barrier();
      __builtin_amdgcn_s_setprio(1);
#pragma unroll
      for (int j = 0; j < 2; j++)
#pragma unroll
        for (int nn = 0; nn < NF; nn++)
#pragma unroll
          for (int kk = 0; kk < 2; kk++)
            acc[p * 2 + j][nn] = MFMA16(af[j][kk], bf[nn][kk], acc[p * 2 + j][nn]);
      __builtin_amdgcn_s_setprio(0);
      if (p == 3) asm volatile("s_waitcnt vmcnt(0)" ::: "memory");  // next tile landed
      __builtin_amdgcn_s_barrier();
    }
  }
  // epilogue: C-write
#pragma unroll
  for (int mm = 0; mm < 8; mm++)
#pragma unroll
    for (int nn = 0; nn < NF; nn++)
#pragma unroll
      for (int r = 0; r < 4; r++) {
        size_t row = m0 + wr * 128 + mm * 16 + g * 4 + r;
        size_t col = n0 + wc * (NF * 16) + nn * 16 + c;
        float v = acc[mm][nn][r];
        if constexpr (OUT_F16)
          ((f16*)Cp)[row * N_ + col] = (f16)v;
        else
          ((float*)Cp)[row * N_ + col] = v;
      }
}

// ---------------- RMSNorm + RoPE + relayout (Q, K only) ----------------
__global__ __launch_bounds__(256) void k_norm_rope(const f16* __restrict__ qkv,
                                                   const int* __restrict__ pos_ids,
                                                   const float* __restrict__ qw,
                                                   const float* __restrict__ kw,
                                                   f16* __restrict__ Qo, f16* __restrict__ Ko) {
  int bt = blockIdx.x;
  int b = bt >> 11, t = bt & 2047;
  int tid = threadIdx.x, w = tid >> 6, lane = tid & 63;
  const f16* row = qkv + (size_t)bt * 3072;
  float pq = (float)pos_ids[t];
  float pk = (float)t;
  float inv = expf(-(float)lane * 0.14391156831212787f);
  for (int hi = w; hi < 20; hi += 4) {
    bool isq = hi < 16;
    int off = isq ? hi * 128 : 2048 + (hi - 16) * 128;
    float x1 = (float)row[off + 2 * lane];
    float x2 = (float)row[off + 2 * lane + 1];
    float ss = x1 * x1 + x2 * x2;
#pragma unroll
    for (int o = 1; o < 64; o <<= 1) ss += __shfl_xor(ss, o);
    float rms = rsqrtf(ss * (1.0f / 128.0f) + 1e-6f);
    const float* wt = isq ? qw : kw;
    float n1 = x1 * rms * wt[2 * lane], n2 = x2 * rms * wt[2 * lane + 1];
    float pos = isq ? pq : pk;
    float ang = pos * inv;
    float sn = sinf(ang), cs = cosf(ang);
    f16 r1 = (f16)(n1 * cs - n2 * sn), r2 = (f16)(n1 * sn + n2 * cs);
    if (isq) {
      f16* dst = Qo + (((size_t)b * HQ + hi) * TT + t) * HD;
      dst[2 * lane] = r1;
      dst[2 * lane + 1] = r2;
    } else {
      f16* dst = Ko + (((size_t)b * HKV + (hi - 16)) * TT + t) * HD;
      dst[2 * lane] = r1;
      dst[2 * lane + 1] = r2;
    }
  }
}

// ------- V transpose: from QKV buffer cols [2560..3072) -> Vt[b][hkv][d][t] -------
__global__ __launch_bounds__(256) void k_trV(const f16* __restrict__ qkv,
                                             f16* __restrict__ Vt) {
  __shared__ f16 tile[32][34];
  int t0 = blockIdx.x * 32, d0 = blockIdx.y * 32;
  int bh = blockIdx.z;
  int b = bh >> 2, hkv = bh & 3;
  int tx = threadIdx.x, ty = threadIdx.y;
  const f16* src = qkv + (size_t)b * 2048 * 3072 + 2560 + hkv * 128;
#pragma unroll
  for (int r = 0; r < 32; r += 8)
    tile[ty + r][tx] = src[(size_t)(t0 + ty + r) * 3072 + d0 + tx];
  __syncthreads();
  f16* dst = Vt + ((size_t)bh * HD + d0) * TT + t0;
#pragma unroll
  for (int r = 0; r < 32; r += 8)
    dst[(size_t)(ty + r) * TT + tx] = tile[tx][ty + r];
}

// ---- attention: 4 waves x 32q, 64-key tiles, swapped QK^T, gload_lds dbuf staging ----
__global__ __launch_bounds__(256, 2) void k_attn2(const f16* __restrict__ Q,
                                                  const f16* __restrict__ Kc,
                                                  const f16* __restrict__ Vt,
                                                  f16* __restrict__ Oa) {
  // double-buffered tiles; LDS linear, swizzle applied on GLOBAL source + on read
  __shared__ alignas(16) char KsC[2][64 * 256];   // K: 64 keys x 128 d (256B rows)
  __shared__ alignas(16) char VsC[2][128 * 128];  // V^T: 128 d x 64 keys (128B rows)
  int qt = blockIdx.x, h = blockIdx.y, b = blockIdx.z;
  // balance remap: CU pairs blocks differing only in b; pair heavy qt with light
  qt = b ? (15 - qt) : qt;
  int q0 = qt * 128, hkv = h >> 2;
  int tid = threadIdx.x;
  int w = tid >> 6, lane = tid & 63, ln = lane & 31, hi = lane >> 5;
  const char* KbB = (const char*)(Kc + ((size_t)b * HKV + hkv) * TT * HD);
  const char* VbB = (const char*)(Vt + ((size_t)b * HKV + hkv) * (size_t)HD * TT);
  int q = q0 + w * 32 + ln;
  const f16* Qp = Q + (((size_t)b * HQ + h) * TT + q) * HD + hi * 8;
  f16x8 qf[8];
#pragma unroll
  for (int st = 0; st < 8; st++) qf[st] = *(const f16x8*)&Qp[st * 16];
  f32x16 o[4] = {};
  float lsum = 0.f;
  int kfswz = (ln & 7) << 4;

  // staging source addressing (dest linear: byte = j*4096 + w*1024 + lane*16)
  int krow0 = w * 4 + (lane >> 4);                       // + j*16 per issue
  int kswzb = ((lane & 15) * 16) ^ ((krow0 & 7) << 4);   // pre-swizzled col byte
  int vrow0 = w * 8 + (lane >> 3);                       // + j*32 per issue
  int vswzb = ((lane & 7) * 16) ^ ((vrow0 & 7) << 4);

  int k0max = (q0 + 127) & ~63;
  int wlo = (q0 - 1023 > 128) ? ((q0 - 1023) & ~63) : 128;
  int nw = (k0max >= wlo) ? ((k0max - wlo) >> 6) + 1 : 0;
  int ntiles = 2 + nw;
  int qw = q0 + w * 32;

  const float C1 = 0.12751791217100872f;  // (1/sqrt(128)) * log2(e)
  const float C2 = 5.7707801635534255f;   // 4.0 * log2(e)  (fixed softmax shift)

  auto stage = [&](int buf, int k0) {
    const char* ks = KbB + (size_t)(k0 + krow0) * 256 + kswzb;
    const char* vs = VbB + (size_t)vrow0 * (TT * 2) + (size_t)k0 * 2 + vswzb;
    char* kd = KsC[buf] + w * 1024;
    char* vd = VsC[buf] + w * 1024;
#pragma unroll
    for (int j = 0; j < 4; j++) gload16(ks + (size_t)j * 4096, kd + j * 4096);
#pragma unroll
    for (int j = 0; j < 4; j++) gload16(vs + (size_t)j * 32 * (TT * 2), vd + j * 4096);
  };

  stage(0, 0);
  __syncthreads();
  int cur = 0;

  for (int ti = 0; ti < ntiles; ti++) {
    int k0 = (ti < 2) ? ti * 64 : wlo + (ti - 2) * 64;
    bool havenext = (ti + 1 < ntiles);
    if (havenext) {  // async loads for next tile; hidden under this tile's compute
      int k0n = (ti + 1 < 2) ? 64 : wlo + (ti - 1) * 64;
      stage(cur ^ 1, k0n);
    }
    bool needmask = false;
    if (ti >= 2) {
      int wsmax = qw + 31 - 1023;
      if (wsmax < 128) wsmax = 128;
      needmask = !((k0 + 63 <= qw) && (k0 >= wsmax));
    }
    f16x8 pa[2][2];
#pragma unroll
    for (int ksub = 0; ksub < 2; ksub++) {
      // two independent accumulator chains halve the MFMA dependency depth
      f32x16 s0 = {}, s1 = {};
      const char* krow = KsC[cur] + (ksub * 32 + ln) * 256;
      __builtin_amdgcn_s_setprio(1);
#pragma unroll
      for (int st = 0; st < 8; st += 2) {
        f16x8 kf0 = *(const f16x8*)(krow + ((st * 32 + hi * 16) ^ kfswz));
        f16x8 kf1 = *(const f16x8*)(krow + (((st + 1) * 32 + hi * 16) ^ kfswz));
        s0 = MFMA32(kf0, qf[st], s0);
        s1 = MFMA32(kf1, qf[st + 1], s1);
      }
      __builtin_amdgcn_s_setprio(0);
      f32x16 s = s0 + s1;
      int qmk = q - (k0 + ksub * 32 + 4 * hi);
      float pr[16];
#pragma unroll
      for (int r = 0; r < 16; r++) {
        float e = fast_exp2(s[r] * C1 - C2);
        if (needmask) {
          int kk = (r & 3) + 8 * (r >> 2);
          e = ((uint32_t)(qmk - kk) < 1024u) ? e : 0.0f;
        }
        lsum += e;
        pr[r] = e;
      }
      uint32_t c[8];
#pragma unroll
      for (int i = 0; i < 8; i++) c[i] = cvt_pk_u32(pr[2 * i], pr[2 * i + 1]);
      // Build PV A-fragments via shfl_xor(32) + per-lane select (validated r7).
      {
        uint32_t x0 = __shfl_xor(c[0], 32), x1 = __shfl_xor(c[1], 32);
        uint32_t x2 = __shfl_xor(c[2], 32), x3 = __shfl_xor(c[3], 32);
        u32x4 t0 = {hi ? x2 : c[0], hi ? x3 : c[1], hi ? c[2] : x0, hi ? c[3] : x1};
        pa[ksub][0] = __builtin_bit_cast(f16x8, t0);
        uint32_t x4 = __shfl_xor(c[4], 32), x5 = __shfl_xor(c[5], 32);
        uint32_t x6 = __shfl_xor(c[6], 32), x7 = __shfl_xor(c[7], 32);
        u32x4 t1 = {hi ? x6 : c[4], hi ? x7 : c[5], hi ? c[6] : x4, hi ? c[7] : x5};
        pa[ksub][1] = __builtin_bit_cast(f16x8, t1);
      }
    }
    // PV: o[q][d] += P[q][k] V[k][d]  (4 independent chains of depth 4)
    __builtin_amdgcn_s_setprio(1);
#pragma unroll
    for (int dsub = 0; dsub < 4; dsub++) {
      const char* vrow = VsC[cur] + (dsub * 32 + ln) * 128;
#pragma unroll
      for (int ksub = 0; ksub < 2; ksub++)
#pragma unroll
        for (int st2 = 0; st2 < 2; st2++) {
          f16x8 vf = *(const f16x8*)(vrow + ((ksub * 64 + st2 * 32 + hi * 16) ^ kfswz));
          o[dsub] = MFMA32(pa[ksub][st2], vf, o[dsub]);
        }
    }
    __builtin_amdgcn_s_setprio(0);
    __syncthreads();  // drains next-tile gload_lds (vmcnt) + all waves done with cur
    cur ^= 1;
  }
  // epilogue: finish l, scale, store
  lsum += __shfl_xor(lsum, 32);
  float rl[16];
#pragma unroll
  for (int r = 0; r < 16; r++) {
    int row = (r & 3) + 8 * (r >> 2) + 4 * hi;
    float lv = __shfl(lsum, row);
    rl[r] = 1.0f / lv;
  }
#pragma unroll
  for (int r = 0; r < 16; r++) {
    int row = (r & 3) + 8 * (r >> 2) + 4 * hi;
    size_t base = ((size_t)b * TT + q0 + w * 32 + row) * DM + (size_t)h * HD + ln;
#pragma unroll
    for (int dsub = 0; dsub < 4; dsub++)
      Oa[base + dsub * 32] = (f16)(o[dsub][r] * rl[r]);
  }
}

extern "C" void kernel_launch(void* const* d_in, const int* in_sizes, int n_in,
                              void* d_out, int out_size, void* d_ws, size_t ws_size,
                              hipStream_t stream) {
  const float* hidden = (const float*)d_in[0];
  const int* pos = (const int*)d_in[1];
  const float* Wq = (const float*)d_in[2];
  const float* Wk = (const float*)d_in[3];
  const float* Wv = (const float*)d_in[4];
  const float* Wo = (const float*)d_in[5];
  const float* qw = (const float*)d_in[6];
  const float* kw = (const float*)d_in[7];
  float* out = (float*)d_out;

  char* p = (char*)d_ws;
  auto take = [&](size_t n) {
    void* r = (void*)p;
    p += (n + 255) & ~(size_t)255;
    return r;
  };
  f16* Xb = (f16*)take((size_t)4096 * 2048 * 2);
  f16* WqkvT = (f16*)take((size_t)3072 * 2048 * 2);
  f16* WoT = (f16*)take((size_t)2048 * 2048 * 2);
  f16* QKVb = (f16*)take((size_t)4096 * 3072 * 2);
  f16* Qr = (f16*)take((size_t)BB * HQ * TT * HD * 2);
  f16* Kr = (f16*)take((size_t)BB * HKV * TT * HD * 2);
  f16* Vt = (f16*)take((size_t)BB * HKV * TT * HD * 2);
  f16* Attn = (f16*)take((size_t)4096 * 2048 * 2);

  dim3 tb(32, 8);
  k_cvt_f16<<<4096, 256, 0, stream>>>(hidden, Xb, 1048576);
  k_tr_cvt<<<dim3(64, 64), tb, 0, stream>>>(Wq, WqkvT, 2048, 2048);
  k_tr_cvt<<<dim3(16, 64), tb, 0, stream>>>(Wk, WqkvT + (size_t)2048 * 2048, 512, 2048);
  k_tr_cvt<<<dim3(16, 64), tb, 0, stream>>>(Wv, WqkvT + (size_t)2560 * 2048, 512, 2048);
  k_tr_cvt<<<dim3(64, 64), tb, 0, stream>>>(Wo, WoT, 2048, 2048);
  k_gemm8<192, 3072, true><<<256, 512, 0, stream>>>(Xb, WqkvT, QKVb, 4096, 2048);
  k_norm_rope<<<4096, 256, 0, stream>>>(QKVb, pos, qw, kw, Qr, Kr);
  k_trV<<<dim3(64, 4, 8), tb, 0, stream>>>(QKVb, Vt);
  k_attn2<<<dim3(16, 16, 2), 256, 0, stream>>>(Qr, Kr, Vt, Attn);
  k_gemm8<128, 2048, false><<<256, 512, 0, stream>>>(Attn, WoT, out, 4096, 2048);
}

// Round 12
// 199.935 us; speedup vs baseline: 1.3776x; 1.0210x over previous
//
#include <hip/hip_runtime.h>
#include <cstdint>
#include <cstddef>

#define DM 2048
#define TT 2048
#define BB 2
#define HQ 16
#define HKV 4
#define HD 128

typedef _Float16 f16;
using f16x8 = __attribute__((ext_vector_type(8))) f16;
using f32x4 = __attribute__((ext_vector_type(4))) float;
using f32x16 = __attribute__((ext_vector_type(16))) float;
using u32x4 = __attribute__((ext_vector_type(4))) uint32_t;

#define MFMA16(a, b, c) __builtin_amdgcn_mfma_f32_16x16x32_f16(a, b, c, 0, 0, 0)
#define MFMA32(a, b, c) __builtin_amdgcn_mfma_f32_32x32x16_f16(a, b, c, 0, 0, 0)

typedef __attribute__((address_space(1))) const void gvoid_t;
typedef __attribute__((address_space(3))) void lvoid_t;
static __device__ __forceinline__ void gload16(const void* g, void* l) {
  __builtin_amdgcn_global_load_lds((gvoid_t*)g, (lvoid_t*)l, 16, 0, 0);
}

static __device__ __forceinline__ float fast_exp2(float x) {
#if __has_builtin(__builtin_amdgcn_exp2f)
  return __builtin_amdgcn_exp2f(x);
#else
  return exp2f(x);
#endif
}

static __device__ __forceinline__ uint32_t cvt_pk_u32(float a, float b) {
  auto h2 = __builtin_amdgcn_cvt_pkrtz(a, b);
  return __builtin_bit_cast(uint32_t, h2);
}

// ---------------- fp32 -> fp16 convert (vectorized) ----------------
__global__ __launch_bounds__(256) void k_cvt_f16(const float* __restrict__ in,
                                                 f16* __restrict__ out, int n8) {
  int i = blockIdx.x * 256 + threadIdx.x;
  if (i >= n8) return;
  const float4* pin = (const float4*)in;
  float4 a = pin[2 * i], b = pin[2 * i + 1];
  f16x8 o = {(f16)a.x, (f16)a.y, (f16)a.z, (f16)a.w,
             (f16)b.x, (f16)b.y, (f16)b.z, (f16)b.w};
  *(f16x8*)&out[(size_t)8 * i] = o;
}

// ------------- transpose + convert: in fp32 [K][N] -> out f16 [N][K] -------------
__global__ __launch_bounds__(256) void k_tr_cvt(const float* __restrict__ in,
                                                f16* __restrict__ out, int N, int ldout) {
  __shared__ float tile[32][33];
  int n0 = blockIdx.x * 32, k0 = blockIdx.y * 32;
  int tx = threadIdx.x, ty = threadIdx.y;
#pragma unroll
  for (int r = 0; r < 32; r += 8) tile[ty + r][tx] = in[(size_t)(k0 + ty + r) * N + n0 + tx];
  __syncthreads();
#pragma unroll
  for (int r = 0; r < 32; r += 8)
    out[(size_t)(n0 + ty + r) * ldout + k0 + tx] = (f16)tile[tx][ty + r];
}

// ---- 8-phase 256xBN MFMA GEMM, barrier-light: 1 vmcnt(0)+barrier per K-tile ----
// C[M,N] = A[M,K] * BT[N,K]^T. 512 threads = 8 waves (2M x 4N), 128 x BN/4 out/wave.
template <int BN_, int N_, bool OUT_F16>
__global__ __launch_bounds__(512, 2) void k_gemm8(const f16* __restrict__ A,
                                                  const f16* __restrict__ BT,
                                                  void* __restrict__ Cp, int M, int K) {
  constexpr int NF = BN_ / 64;   // 16-col B-fragments per wave
  constexpr int BI = BN_ / 64;   // B staging issues (64 rows each)
  __shared__ alignas(16) char Abuf[2][256 * 128];  // 256 rows x 128B, linear
  __shared__ alignas(16) char Bbuf[2][BN_ * 128];
  constexpr int NT = N_ / BN_;
  int bid = blockIdx.x;
  int m0 = (bid / NT) * 256, n0 = (bid % NT) * BN_;
  int tid = threadIdx.x;
  int lane = tid & 63, w = tid >> 6;
  int wr = w >> 2, wc = w & 3;
  int g = lane >> 4, c = lane & 15;
  int rswz = (c & 7) << 4;  // read-side XOR (fragment row&7 == c&7)

  // staging: issue i covers rows 64i..64i+63; source pre-swizzled so that
  // linear LDS[row][cb] == global[row][cb ^ ((row&7)<<4)]
  int srow = tid >> 3;                     // 0..63 within issue
  int scbs = ((tid & 7) * 16) ^ ((srow & 7) << 4);
  const char* Ag = (const char*)A + (size_t)(m0 + srow) * (K * 2) + scbs;
  const char* Bg = (const char*)BT + (size_t)(n0 + srow) * (K * 2) + scbs;
  int lbase = w * 1024;  // wave-uniform LDS base; HW adds lane*16

  f32x4 acc[8][NF] = {};
  int nk = K >> 6;

  auto stageA = [&](int buf, int kt, int i) {
    gload16(Ag + (size_t)(i * 64) * (K * 2) + (size_t)kt * 128,
            &Abuf[buf][i * 8192 + lbase]);
  };
  auto stageB = [&](int buf, int kt, int i) {
    gload16(Bg + (size_t)(i * 64) * (K * 2) + (size_t)kt * 128,
            &Bbuf[buf][i * 8192 + lbase]);
  };

  // prologue: stage K-tile 0 into buf 0, drain, publish
  {
#pragma unroll
    for (int i = 0; i < 4; i++) stageA(0, 0, i);
#pragma unroll
    for (int i = 0; i < BI; i++) stageB(0, 0, i);
    asm volatile("s_waitcnt vmcnt(0)" ::: "memory");
    __builtin_amdgcn_s_barrier();
  }

  for (int kt = 0; kt < nk; kt++) {
    int cur = kt & 1, nxt = cur ^ 1;
    bool more = (kt + 1) < nk;
    const char* Ab = Abuf[cur];
    const char* Bb = Bbuf[cur];
    f16x8 bf[NF][2], af[2][2];
#pragma unroll
    for (int p = 0; p < 4; p++) {
      if (p == 0) {
#pragma unroll
        for (int nn = 0; nn < NF; nn++)
#pragma unroll
          for (int kk = 0; kk < 2; kk++) {
            int R = wc * (NF * 16) + nn * 16 + c;
            bf[nn][kk] = *(const f16x8*)(Bb + R * 128 + ((kk * 64 + g * 16) ^ rswz));
          }
      }
#pragma unroll
      for (int j = 0; j < 2; j++)
#pragma unroll
        for (int kk = 0; kk < 2; kk++) {
          int R = wr * 128 + (p * 2 + j) * 16 + c;
          af[j][kk] = *(const f16x8*)(Ab + R * 128 + ((kk * 64 + g * 16) ^ rswz));
        }
      // issue-early: all next-tile loads go out in phases 0-1 (max slack to drain)
      if (more) {
        if (p == 0) {
          stageA(nxt, kt + 1, 0); stageA(nxt, kt + 1, 1); stageB(nxt, kt + 1, 0);
        } else if (p == 1) {
          stageA(nxt, kt + 1, 2); stageA(nxt, kt + 1, 3); stageB(nxt, kt + 1, 1);
          if constexpr (BI == 3) stageB(nxt, kt + 1, 2);
        }
      }
      __builtin_amdgcn_s_barrier();  // pre-MFMA lockstep (no post-MFMA barrier:
                                     // phase p+1 ds_reads overlap phase p MFMA)
      __builtin_amdgcn_s_setprio(1);
#pragma unroll
      for (int j = 0; j < 2; j++)
#pragma unroll
        for (int nn = 0; nn < NF; nn++)
#pragma unroll
          for (int kk = 0; kk < 2; kk++)
            acc[p * 2 + j][nn] = MFMA16(af[j][kk], bf[nn][kk], acc[p * 2 + j][nn]);
      __builtin_amdgcn_s_setprio(0);
    }
    // K-tile boundary: the only full drain — next tile's LDS image must be
    // complete (vmcnt) and all waves done reading buf[cur] (barrier).
    asm volatile("s_waitcnt vmcnt(0)" ::: "memory");
    __builtin_amdgcn_s_barrier();
  }
  // epilogue: C-write
#pragma unroll
  for (int mm = 0; mm < 8; mm++)
#pragma unroll
    for (int nn = 0; nn < NF; nn++)
#pragma unroll
      for (int r = 0; r < 4; r++) {
        size_t row = m0 + wr * 128 + mm * 16 + g * 4 + r;
        size_t col = n0 + wc * (NF * 16) + nn * 16 + c;
        float v = acc[mm][nn][r];
        if constexpr (OUT_F16)
          ((f16*)Cp)[row * N_ + col] = (f16)v;
        else
          ((float*)Cp)[row * N_ + col] = v;
      }
}

// ---------------- RMSNorm + RoPE + relayout (Q, K only) ----------------
__global__ __launch_bounds__(256) void k_norm_rope(const f16* __restrict__ qkv,
                                                   const int* __restrict__ pos_ids,
                                                   const float* __restrict__ qw,
                                                   const float* __restrict__ kw,
                                                   f16* __restrict__ Qo, f16* __restrict__ Ko) {
  int bt = blockIdx.x;
  int b = bt >> 11, t = bt & 2047;
  int tid = threadIdx.x, w = tid >> 6, lane = tid & 63;
  const f16* row = qkv + (size_t)bt * 3072;
  float pq = (float)pos_ids[t];
  float pk = (float)t;
  float inv = expf(-(float)lane * 0.14391156831212787f);
  // trig depends only on (pos, lane) — hoist out of the head loop
  float aq = pq * inv, ak = pk * inv;
  float snq = sinf(aq), csq = cosf(aq);
  float snk = sinf(ak), csk = cosf(ak);
  for (int hi = w; hi < 20; hi += 4) {
    bool isq = hi < 16;
    int off = isq ? hi * 128 : 2048 + (hi - 16) * 128;
    float x1 = (float)row[off + 2 * lane];
    float x2 = (float)row[off + 2 * lane + 1];
    float ss = x1 * x1 + x2 * x2;
#pragma unroll
    for (int o = 1; o < 64; o <<= 1) ss += __shfl_xor(ss, o);
    float rms = rsqrtf(ss * (1.0f / 128.0f) + 1e-6f);
    const float* wt = isq ? qw : kw;
    float n1 = x1 * rms * wt[2 * lane], n2 = x2 * rms * wt[2 * lane + 1];
    float sn = isq ? snq : snk, cs = isq ? csq : csk;
    f16 r1 = (f16)(n1 * cs - n2 * sn), r2 = (f16)(n1 * sn + n2 * cs);
    if (isq) {
      f16* dst = Qo + (((size_t)b * HQ + hi) * TT + t) * HD;
      dst[2 * lane] = r1;
      dst[2 * lane + 1] = r2;
    } else {
      f16* dst = Ko + (((size_t)b * HKV + (hi - 16)) * TT + t) * HD;
      dst[2 * lane] = r1;
      dst[2 * lane + 1] = r2;
    }
  }
}

// ------- V transpose: from QKV buffer cols [2560..3072) -> Vt[b][hkv][d][t] -------
__global__ __launch_bounds__(256) void k_trV(const f16* __restrict__ qkv,
                                             f16* __restrict__ Vt) {
  __shared__ f16 tile[32][34];
  int t0 = blockIdx.x * 32, d0 = blockIdx.y * 32;
  int bh = blockIdx.z;
  int b = bh >> 2, hkv = bh & 3;
  int tx = threadIdx.x, ty = threadIdx.y;
  const f16* src = qkv + (size_t)b * 2048 * 3072 + 2560 + hkv * 128;
#pragma unroll
  for (int r = 0; r < 32; r += 8)
    tile[ty + r][tx] = src[(size_t)(t0 + ty + r) * 3072 + d0 + tx];
  __syncthreads();
  f16* dst = Vt + ((size_t)bh * HD + d0) * TT + t0;
#pragma unroll
  for (int r = 0; r < 32; r += 8)
    dst[(size_t)(ty + r) * TT + tx] = tile[tx][ty + r];
}

// ---- attention: 4 waves x 32q, 64-key tiles, swapped QK^T, gload_lds dbuf staging ----
__global__ __launch_bounds__(256, 2) void k_attn2(const f16* __restrict__ Q,
                                                  const f16* __restrict__ Kc,
                                                  const f16* __restrict__ Vt,
                                                  f16* __restrict__ Oa) {
  // double-buffered tiles; LDS linear, swizzle applied on GLOBAL source + on read
  __shared__ alignas(16) char KsC[2][64 * 256];   // K: 64 keys x 128 d (256B rows)
  __shared__ alignas(16) char VsC[2][128 * 128];  // V^T: 128 d x 64 keys (128B rows)
  int qt = blockIdx.x, h = blockIdx.y, b = blockIdx.z;
  // balance remap: CU pairs blocks differing only in b; pair heavy qt with light
  qt = b ? (15 - qt) : qt;
  int q0 = qt * 128, hkv = h >> 2;
  int tid = threadIdx.x;
  int w = tid >> 6, lane = tid & 63, ln = lane & 31, hi = lane >> 5;
  const char* KbB = (const char*)(Kc + ((size_t)b * HKV + hkv) * TT * HD);
  const char* VbB = (const char*)(Vt + ((size_t)b * HKV + hkv) * (size_t)HD * TT);
  int q = q0 + w * 32 + ln;
  const f16* Qp = Q + (((size_t)b * HQ + h) * TT + q) * HD + hi * 8;
  f16x8 qf[8];
#pragma unroll
  for (int st = 0; st < 8; st++) qf[st] = *(const f16x8*)&Qp[st * 16];
  f32x16 o[4] = {};
  float lsum = 0.f;
  int kfswz = (ln & 7) << 4;

  // staging source addressing (dest linear: byte = j*4096 + w*1024 + lane*16)
  int krow0 = w * 4 + (lane >> 4);                       // + j*16 per issue
  int kswzb = ((lane & 15) * 16) ^ ((krow0 & 7) << 4);   // pre-swizzled col byte
  int vrow0 = w * 8 + (lane >> 3);                       // + j*32 per issue
  int vswzb = ((lane & 7) * 16) ^ ((vrow0 & 7) << 4);

  int k0max = (q0 + 127) & ~63;
  int wlo = (q0 - 1023 > 128) ? ((q0 - 1023) & ~63) : 128;
  int nw = (k0max >= wlo) ? ((k0max - wlo) >> 6) + 1 : 0;
  int ntiles = 2 + nw;
  int qw = q0 + w * 32;

  const float C1 = 0.12751791217100872f;  // (1/sqrt(128)) * log2(e)
  const float C2 = 5.7707801635534255f;   // 4.0 * log2(e)  (fixed softmax shift)

  auto stage = [&](int buf, int k0) {
    const char* ks = KbB + (size_t)(k0 + krow0) * 256 + kswzb;
    const char* vs = VbB + (size_t)vrow0 * (TT * 2) + (size_t)k0 * 2 + vswzb;
    char* kd = KsC[buf] + w * 1024;
    char* vd = VsC[buf] + w * 1024;
#pragma unroll
    for (int j = 0; j < 4; j++) gload16(ks + (size_t)j * 4096, kd + j * 4096);
#pragma unroll
    for (int j = 0; j < 4; j++) gload16(vs + (size_t)j * 32 * (TT * 2), vd + j * 4096);
  };

  stage(0, 0);
  __syncthreads();
  int cur = 0;

  for (int ti = 0; ti < ntiles; ti++) {
    int k0 = (ti < 2) ? ti * 64 : wlo + (ti - 2) * 64;
    bool havenext = (ti + 1 < ntiles);
    if (havenext) {  // async loads for next tile; hidden under this tile's compute
      int k0n = (ti + 1 < 2) ? 64 : wlo + (ti - 1) * 64;
      stage(cur ^ 1, k0n);
    }
    bool needmask = false;
    if (ti >= 2) {
      int wsmax = qw + 31 - 1023;
      if (wsmax < 128) wsmax = 128;
      needmask = !((k0 + 63 <= qw) && (k0 >= wsmax));
    }
    f16x8 pa[2][2];
#pragma unroll
    for (int ksub = 0; ksub < 2; ksub++) {
      // two independent accumulator chains halve the MFMA dependency depth
      f32x16 s0 = {}, s1 = {};
      const char* krow = KsC[cur] + (ksub * 32 + ln) * 256;
      __builtin_amdgcn_s_setprio(1);
#pragma unroll
      for (int st = 0; st < 8; st += 2) {
        f16x8 kf0 = *(const f16x8*)(krow + ((st * 32 + hi * 16) ^ kfswz));
        f16x8 kf1 = *(const f16x8*)(krow + (((st + 1) * 32 + hi * 16) ^ kfswz));
        s0 = MFMA32(kf0, qf[st], s0);
        s1 = MFMA32(kf1, qf[st + 1], s1);
      }
      __builtin_amdgcn_s_setprio(0);
      f32x16 s = s0 + s1;
      int qmk = q - (k0 + ksub * 32 + 4 * hi);
      float pr[16];
#pragma unroll
      for (int r = 0; r < 16; r++) {
        float e = fast_exp2(s[r] * C1 - C2);
        if (needmask) {
          int kk = (r & 3) + 8 * (r >> 2);
          e = ((uint32_t)(qmk - kk) < 1024u) ? e : 0.0f;
        }
        lsum += e;
        pr[r] = e;
      }
      uint32_t c[8];
#pragma unroll
      for (int i = 0; i < 8; i++) c[i] = cvt_pk_u32(pr[2 * i], pr[2 * i + 1]);
      // Build PV A-fragments via shfl_xor(32) + per-lane select (validated r7).
      {
        uint32_t x0 = __shfl_xor(c[0], 32), x1 = __shfl_xor(c[1], 32);
        uint32_t x2 = __shfl_xor(c[2], 32), x3 = __shfl_xor(c[3], 32);
        u32x4 t0 = {hi ? x2 : c[0], hi ? x3 : c[1], hi ? c[2] : x0, hi ? c[3] : x1};
        pa[ksub][0] = __builtin_bit_cast(f16x8, t0);
        uint32_t x4 = __shfl_xor(c[4], 32), x5 = __shfl_xor(c[5], 32);
        uint32_t x6 = __shfl_xor(c[6], 32), x7 = __shfl_xor(c[7], 32);
        u32x4 t1 = {hi ? x6 : c[4], hi ? x7 : c[5], hi ? c[6] : x4, hi ? c[7] : x5};
        pa[ksub][1] = __builtin_bit_cast(f16x8, t1);
      }
    }
    // PV: o[q][d] += P[q][k] V[k][d]  (4 independent chains of depth 4)
    __builtin_amdgcn_s_setprio(1);
#pragma unroll
    for (int dsub = 0; dsub < 4; dsub++) {
      const char* vrow = VsC[cur] + (dsub * 32 + ln) * 128;
#pragma unroll
      for (int ksub = 0; ksub < 2; ksub++)
#pragma unroll
        for (int st2 = 0; st2 < 2; st2++) {
          f16x8 vf = *(const f16x8*)(vrow + ((ksub * 64 + st2 * 32 + hi * 16) ^ kfswz));
          o[dsub] = MFMA32(pa[ksub][st2], vf, o[dsub]);
        }
    }
    __builtin_amdgcn_s_setprio(0);
    __syncthreads();  // drains next-tile gload_lds (vmcnt) + all waves done with cur
    cur ^= 1;
  }
  // epilogue: finish l, scale, store
  lsum += __shfl_xor(lsum, 32);
  float rl[16];
#pragma unroll
  for (int r = 0; r < 16; r++) {
    int row = (r & 3) + 8 * (r >> 2) + 4 * hi;
    float lv = __shfl(lsum, row);
    rl[r] = 1.0f / lv;
  }
#pragma unroll
  for (int r = 0; r < 16; r++) {
    int row = (r & 3) + 8 * (r >> 2) + 4 * hi;
    size_t base = ((size_t)b * TT + q0 + w * 32 + row) * DM + (size_t)h * HD + ln;
#pragma unroll
    for (int dsub = 0; dsub < 4; dsub++)
      Oa[base + dsub * 32] = (f16)(o[dsub][r] * rl[r]);
  }
}

extern "C" void kernel_launch(void* const* d_in, const int* in_sizes, int n_in,
                              void* d_out, int out_size, void* d_ws, size_t ws_size,
                              hipStream_t stream) {
  const float* hidden = (const float*)d_in[0];
  const int* pos = (const int*)d_in[1];
  const float* Wq = (const float*)d_in[2];
  const float* Wk = (const float*)d_in[3];
  const float* Wv = (const float*)d_in[4];
  const float* Wo = (const float*)d_in[5];
  const float* qw = (const float*)d_in[6];
  const float* kw = (const float*)d_in[7];
  float* out = (float*)d_out;

  char* p = (char*)d_ws;
  auto take = [&](size_t n) {
    void* r = (void*)p;
    p += (n + 255) & ~(size_t)255;
    return r;
  };
  f16* Xb = (f16*)take((size_t)4096 * 2048 * 2);
  f16* WqkvT = (f16*)take((size_t)3072 * 2048 * 2);
  f16* WoT = (f16*)take((size_t)2048 * 2048 * 2);
  f16* QKVb = (f16*)take((size_t)4096 * 3072 * 2);
  f16* Qr = (f16*)take((size_t)BB * HQ * TT * HD * 2);
  f16* Kr = (f16*)take((size_t)BB * HKV * TT * HD * 2);
  f16* Vt = (f16*)take((size_t)BB * HKV * TT * HD * 2);
  f16* Attn = (f16*)take((size_t)4096 * 2048 * 2);

  dim3 tb(32, 8);
  k_cvt_f16<<<4096, 256, 0, stream>>>(hidden, Xb, 1048576);
  k_tr_cvt<<<dim3(64, 64), tb, 0, stream>>>(Wq, WqkvT, 2048, 2048);
  k_tr_cvt<<<dim3(16, 64), tb, 0, stream>>>(Wk, WqkvT + (size_t)2048 * 2048, 512, 2048);
  k_tr_cvt<<<dim3(16, 64), tb, 0, stream>>>(Wv, WqkvT + (size_t)2560 * 2048, 512, 2048);
  k_tr_cvt<<<dim3(64, 64), tb, 0, stream>>>(Wo, WoT, 2048, 2048);
  k_gemm8<192, 3072, true><<<256, 512, 0, stream>>>(Xb, WqkvT, QKVb, 4096, 2048);
  k_norm_rope<<<4096, 256, 0, stream>>>(QKVb, pos, qw, kw, Qr, Kr);
  k_trV<<<dim3(64, 4, 8), tb, 0, stream>>>(QKVb, Vt);
  k_attn2<<<dim3(16, 16, 2), 256, 0, stream>>>(Qr, Kr, Vt, Attn);
  k_gemm8<128, 2048, false><<<256, 512, 0, stream>>>(Attn, WoT, out, 4096, 2048);
}

// Round 13
// 197.833 us; speedup vs baseline: 1.3922x; 1.0106x over previous
//
#include <hip/hip_runtime.h>
#include <cstdint>
#include <cstddef>

#define DM 2048
#define TT 2048
#define BB 2
#define HQ 16
#define HKV 4
#define HD 128

typedef _Float16 f16;
using f16x8 = __attribute__((ext_vector_type(8))) f16;
using f32x4 = __attribute__((ext_vector_type(4))) float;
using f32x16 = __attribute__((ext_vector_type(16))) float;
using u32x4 = __attribute__((ext_vector_type(4))) uint32_t;

#define MFMA16(a, b, c) __builtin_amdgcn_mfma_f32_16x16x32_f16(a, b, c, 0, 0, 0)
#define MFMA32(a, b, c) __builtin_amdgcn_mfma_f32_32x32x16_f16(a, b, c, 0, 0, 0)

typedef __attribute__((address_space(1))) const void gvoid_t;
typedef __attribute__((address_space(3))) void lvoid_t;
static __device__ __forceinline__ void gload16(const void* g, void* l) {
  __builtin_amdgcn_global_load_lds((gvoid_t*)g, (lvoid_t*)l, 16, 0, 0);
}

static __device__ __forceinline__ float fast_exp2(float x) {
#if __has_builtin(__builtin_amdgcn_exp2f)
  return __builtin_amdgcn_exp2f(x);
#else
  return exp2f(x);
#endif
}

static __device__ __forceinline__ uint32_t cvt_pk_u32(float a, float b) {
  auto h2 = __builtin_amdgcn_cvt_pkrtz(a, b);
  return __builtin_bit_cast(uint32_t, h2);
}

// ---------------- fp32 -> fp16 convert (vectorized) ----------------
__global__ __launch_bounds__(256) void k_cvt_f16(const float* __restrict__ in,
                                                 f16* __restrict__ out, int n8) {
  int i = blockIdx.x * 256 + threadIdx.x;
  if (i >= n8) return;
  const float4* pin = (const float4*)in;
  float4 a = pin[2 * i], b = pin[2 * i + 1];
  f16x8 o = {(f16)a.x, (f16)a.y, (f16)a.z, (f16)a.w,
             (f16)b.x, (f16)b.y, (f16)b.z, (f16)b.w};
  *(f16x8*)&out[(size_t)8 * i] = o;
}

// ------ all weight transposes in one launch: fp32 [K][N] -> f16 [N][K] tiles ------
__global__ __launch_bounds__(256) void k_tr_all(const float* __restrict__ Wq,
                                                const float* __restrict__ Wk,
                                                const float* __restrict__ Wv,
                                                const float* __restrict__ Wo,
                                                f16* __restrict__ WqkvT,
                                                f16* __restrict__ WoT) {
  __shared__ float tile[32][33];
  int t = blockIdx.x;
  const float* in;
  f16* out;
  int N, nx;
  if (t < 4096) {
    in = Wq; out = WqkvT; N = 2048; nx = 64;
  } else if (t < 5120) {
    t -= 4096; in = Wk; out = WqkvT + (size_t)2048 * 2048; N = 512; nx = 16;
  } else if (t < 6144) {
    t -= 5120; in = Wv; out = WqkvT + (size_t)2560 * 2048; N = 512; nx = 16;
  } else {
    t -= 6144; in = Wo; out = WoT; N = 2048; nx = 64;
  }
  int n0 = (t % nx) * 32, k0 = (t / nx) * 32;
  int tx = threadIdx.x, ty = threadIdx.y;
#pragma unroll
  for (int r = 0; r < 32; r += 8) tile[ty + r][tx] = in[(size_t)(k0 + ty + r) * N + n0 + tx];
  __syncthreads();
#pragma unroll
  for (int r = 0; r < 32; r += 8)
    out[(size_t)(n0 + ty + r) * 2048 + k0 + tx] = (f16)tile[tx][ty + r];
}

// ---- 8-phase 256xBN MFMA GEMM, barrier-light + XCD-swizzled block mapping ----
// C[M,N] = A[M,K] * BT[N,K]^T. 512 threads = 8 waves (2M x 4N), 128 x BN/4 out/wave.
template <int BN_, int N_, bool OUT_F16>
__global__ __launch_bounds__(512, 2) void k_gemm8(const f16* __restrict__ A,
                                                  const f16* __restrict__ BT,
                                                  void* __restrict__ Cp, int M, int K) {
  constexpr int NF = BN_ / 64;   // 16-col B-fragments per wave
  constexpr int BI = BN_ / 64;   // B staging issues (64 rows each)
  __shared__ alignas(16) char Abuf[2][256 * 128];  // 256 rows x 128B, linear
  __shared__ alignas(16) char Bbuf[2][BN_ * 128];
  constexpr int NT = N_ / BN_;
  // T1: XCD-aware bijective remap (gridDim.x == 256, 8 XCDs round-robin)
  int bid0 = blockIdx.x;
  int bid = (bid0 & 7) * (gridDim.x >> 3) + (bid0 >> 3);
  int m0 = (bid / NT) * 256, n0 = (bid % NT) * BN_;
  int tid = threadIdx.x;
  int lane = tid & 63, w = tid >> 6;
  int wr = w >> 2, wc = w & 3;
  int g = lane >> 4, c = lane & 15;
  int rswz = (c & 7) << 4;  // read-side XOR (fragment row&7 == c&7)

  // staging: issue i covers rows 64i..64i+63; source pre-swizzled so that
  // linear LDS[row][cb] == global[row][cb ^ ((row&7)<<4)]
  int srow = tid >> 3;                     // 0..63 within issue
  int scbs = ((tid & 7) * 16) ^ ((srow & 7) << 4);
  const char* Ag = (const char*)A + (size_t)(m0 + srow) * (K * 2) + scbs;
  const char* Bg = (const char*)BT + (size_t)(n0 + srow) * (K * 2) + scbs;
  int lbase = w * 1024;  // wave-uniform LDS base; HW adds lane*16

  f32x4 acc[8][NF] = {};
  int nk = K >> 6;

  auto stageA = [&](int buf, int kt, int i) {
    gload16(Ag + (size_t)(i * 64) * (K * 2) + (size_t)kt * 128,
            &Abuf[buf][i * 8192 + lbase]);
  };
  auto stageB = [&](int buf, int kt, int i) {
    gload16(Bg + (size_t)(i * 64) * (K * 2) + (size_t)kt * 128,
            &Bbuf[buf][i * 8192 + lbase]);
  };

  // prologue: stage K-tile 0 into buf 0, drain, publish
  {
#pragma unroll
    for (int i = 0; i < 4; i++) stageA(0, 0, i);
#pragma unroll
    for (int i = 0; i < BI; i++) stageB(0, 0, i);
    asm volatile("s_waitcnt vmcnt(0)" ::: "memory");
    __builtin_amdgcn_s_barrier();
  }

  for (int kt = 0; kt < nk; kt++) {
    int cur = kt & 1, nxt = cur ^ 1;
    bool more = (kt + 1) < nk;
    const char* Ab = Abuf[cur];
    const char* Bb = Bbuf[cur];
    f16x8 bf[NF][2], af[2][2];
#pragma unroll
    for (int p = 0; p < 4; p++) {
      if (p == 0) {
#pragma unroll
        for (int nn = 0; nn < NF; nn++)
#pragma unroll
          for (int kk = 0; kk < 2; kk++) {
            int R = wc * (NF * 16) + nn * 16 + c;
            bf[nn][kk] = *(const f16x8*)(Bb + R * 128 + ((kk * 64 + g * 16) ^ rswz));
          }
      }
#pragma unroll
      for (int j = 0; j < 2; j++)
#pragma unroll
        for (int kk = 0; kk < 2; kk++) {
          int R = wr * 128 + (p * 2 + j) * 16 + c;
          af[j][kk] = *(const f16x8*)(Ab + R * 128 + ((kk * 64 + g * 16) ^ rswz));
        }
      // issue-early: all next-tile loads go out in phases 0-1 (max slack to drain)
      if (more) {
        if (p == 0) {
          stageA(nxt, kt + 1, 0); stageA(nxt, kt + 1, 1); stageB(nxt, kt + 1, 0);
        } else if (p == 1) {
          stageA(nxt, kt + 1, 2); stageA(nxt, kt + 1, 3); stageB(nxt, kt + 1, 1);
          if constexpr (BI == 3) stageB(nxt, kt + 1, 2);
        }
      }
      __builtin_amdgcn_s_barrier();  // pre-MFMA lockstep (no post-MFMA barrier:
                                     // phase p+1 ds_reads overlap phase p MFMA)
      __builtin_amdgcn_s_setprio(1);
#pragma unroll
      for (int j = 0; j < 2; j++)
#pragma unroll
        for (int nn = 0; nn < NF; nn++)
#pragma unroll
          for (int kk = 0; kk < 2; kk++)
            acc[p * 2 + j][nn] = MFMA16(af[j][kk], bf[nn][kk], acc[p * 2 + j][nn]);
      __builtin_amdgcn_s_setprio(0);
    }
    // K-tile boundary: the only full drain — next tile's LDS image must be
    // complete (vmcnt) and all waves done reading buf[cur] (barrier).
    asm volatile("s_waitcnt vmcnt(0)" ::: "memory");
    __builtin_amdgcn_s_barrier();
  }
  // epilogue: C-write
#pragma unroll
  for (int mm = 0; mm < 8; mm++)
#pragma unroll
    for (int nn = 0; nn < NF; nn++)
#pragma unroll
      for (int r = 0; r < 4; r++) {
        size_t row = m0 + wr * 128 + mm * 16 + g * 4 + r;
        size_t col = n0 + wc * (NF * 16) + nn * 16 + c;
        float v = acc[mm][nn][r];
        if constexpr (OUT_F16)
          ((f16*)Cp)[row * N_ + col] = (f16)v;
        else
          ((float*)Cp)[row * N_ + col] = v;
      }
}

// ---------------- RMSNorm + RoPE + relayout (Q, K only) ----------------
__global__ __launch_bounds__(256) void k_norm_rope(const f16* __restrict__ qkv,
                                                   const int* __restrict__ pos_ids,
                                                   const float* __restrict__ qw,
                                                   const float* __restrict__ kw,
                                                   f16* __restrict__ Qo, f16* __restrict__ Ko) {
  int bt = blockIdx.x;
  int b = bt >> 11, t = bt & 2047;
  int tid = threadIdx.x, w = tid >> 6, lane = tid & 63;
  const f16* row = qkv + (size_t)bt * 3072;
  float pq = (float)pos_ids[t];
  float pk = (float)t;
  float inv = expf(-(float)lane * 0.14391156831212787f);
  // trig depends only on (pos, lane) — hoist out of the head loop
  float aq = pq * inv, ak = pk * inv;
  float snq = sinf(aq), csq = cosf(aq);
  float snk = sinf(ak), csk = cosf(ak);
  for (int hi = w; hi < 20; hi += 4) {
    bool isq = hi < 16;
    int off = isq ? hi * 128 : 2048 + (hi - 16) * 128;
    float x1 = (float)row[off + 2 * lane];
    float x2 = (float)row[off + 2 * lane + 1];
    float ss = x1 * x1 + x2 * x2;
#pragma unroll
    for (int o = 1; o < 64; o <<= 1) ss += __shfl_xor(ss, o);
    float rms = rsqrtf(ss * (1.0f / 128.0f) + 1e-6f);
    const float* wt = isq ? qw : kw;
    float n1 = x1 * rms * wt[2 * lane], n2 = x2 * rms * wt[2 * lane + 1];
    float sn = isq ? snq : snk, cs = isq ? csq : csk;
    f16 r1 = (f16)(n1 * cs - n2 * sn), r2 = (f16)(n1 * sn + n2 * cs);
    if (isq) {
      f16* dst = Qo + (((size_t)b * HQ + hi) * TT + t) * HD;
      dst[2 * lane] = r1;
      dst[2 * lane + 1] = r2;
    } else {
      f16* dst = Ko + (((size_t)b * HKV + (hi - 16)) * TT + t) * HD;
      dst[2 * lane] = r1;
      dst[2 * lane + 1] = r2;
    }
  }
}

// ------- V transpose: from QKV buffer cols [2560..3072) -> Vt[b][hkv][d][t] -------
__global__ __launch_bounds__(256) void k_trV(const f16* __restrict__ qkv,
                                             f16* __restrict__ Vt) {
  __shared__ f16 tile[32][34];
  int t0 = blockIdx.x * 32, d0 = blockIdx.y * 32;
  int bh = blockIdx.z;
  int b = bh >> 2, hkv = bh & 3;
  int tx = threadIdx.x, ty = threadIdx.y;
  const f16* src = qkv + (size_t)b * 2048 * 3072 + 2560 + hkv * 128;
#pragma unroll
  for (int r = 0; r < 32; r += 8)
    tile[ty + r][tx] = src[(size_t)(t0 + ty + r) * 3072 + d0 + tx];
  __syncthreads();
  f16* dst = Vt + ((size_t)bh * HD + d0) * TT + t0;
#pragma unroll
  for (int r = 0; r < 32; r += 8)
    dst[(size_t)(ty + r) * TT + tx] = tile[tx][ty + r];
}

// ---- attention: 4 waves x 32q, 64-key tiles, swapped QK^T, gload_lds dbuf staging ----
__global__ __launch_bounds__(256, 2) void k_attn2(const f16* __restrict__ Q,
                                                  const f16* __restrict__ Kc,
                                                  const f16* __restrict__ Vt,
                                                  f16* __restrict__ Oa) {
  // double-buffered tiles; LDS linear, swizzle applied on GLOBAL source + on read
  __shared__ alignas(16) char KsC[2][64 * 256];   // K: 64 keys x 128 d (256B rows)
  __shared__ alignas(16) char VsC[2][128 * 128];  // V^T: 128 d x 64 keys (128B rows)
  int qt = blockIdx.x, h = blockIdx.y, b = blockIdx.z;
  // pairing remap: consecutive bids (2i,2i+1) -> (i, 15-i): heavy+light co-resident
  qt = (qt & 1) ? (15 - (qt >> 1)) : (qt >> 1);
  int q0 = qt * 128, hkv = h >> 2;
  int tid = threadIdx.x;
  int w = tid >> 6, lane = tid & 63, ln = lane & 31, hi = lane >> 5;
  const char* KbB = (const char*)(Kc + ((size_t)b * HKV + hkv) * TT * HD);
  const char* VbB = (const char*)(Vt + ((size_t)b * HKV + hkv) * (size_t)HD * TT);
  int q = q0 + w * 32 + ln;
  const f16* Qp = Q + (((size_t)b * HQ + h) * TT + q) * HD + hi * 8;
  f16x8 qf[8];
#pragma unroll
  for (int st = 0; st < 8; st++) qf[st] = *(const f16x8*)&Qp[st * 16];
  f32x16 o[4] = {};
  float lsum = 0.f;
  int kfswz = (ln & 7) << 4;

  // staging source addressing (dest linear: byte = j*4096 + w*1024 + lane*16)
  int krow0 = w * 4 + (lane >> 4);                       // + j*16 per issue
  int kswzb = ((lane & 15) * 16) ^ ((krow0 & 7) << 4);   // pre-swizzled col byte
  int vrow0 = w * 8 + (lane >> 3);                       // + j*32 per issue
  int vswzb = ((lane & 7) * 16) ^ ((vrow0 & 7) << 4);

  int k0max = (q0 + 127) & ~63;
  int wlo = (q0 - 1023 > 128) ? ((q0 - 1023) & ~63) : 128;
  int nw = (k0max >= wlo) ? ((k0max - wlo) >> 6) + 1 : 0;
  int ntiles = 2 + nw;
  int qw = q0 + w * 32;

  const float C1 = 0.12751791217100872f;  // (1/sqrt(128)) * log2(e)
  const float C2 = 5.7707801635534255f;   // 4.0 * log2(e)  (fixed softmax shift)

  auto stage = [&](int buf, int k0) {
    const char* ks = KbB + (size_t)(k0 + krow0) * 256 + kswzb;
    const char* vs = VbB + (size_t)vrow0 * (TT * 2) + (size_t)k0 * 2 + vswzb;
    char* kd = KsC[buf] + w * 1024;
    char* vd = VsC[buf] + w * 1024;
#pragma unroll
    for (int j = 0; j < 4; j++) gload16(ks + (size_t)j * 4096, kd + j * 4096);
#pragma unroll
    for (int j = 0; j < 4; j++) gload16(vs + (size_t)j * 32 * (TT * 2), vd + j * 4096);
  };

  stage(0, 0);
  __syncthreads();
  int cur = 0;

  for (int ti = 0; ti < ntiles; ti++) {
    int k0 = (ti < 2) ? ti * 64 : wlo + (ti - 2) * 64;
    bool havenext = (ti + 1 < ntiles);
    if (havenext) {  // async loads for next tile; hidden under this tile's compute
      int k0n = (ti + 1 < 2) ? 64 : wlo + (ti - 1) * 64;
      stage(cur ^ 1, k0n);
    }
    bool needmask = false;
    if (ti >= 2) {
      int wsmax = qw + 31 - 1023;
      if (wsmax < 128) wsmax = 128;
      needmask = !((k0 + 63 <= qw) && (k0 >= wsmax));
    }
    f16x8 pa[2][2];
#pragma unroll
    for (int ksub = 0; ksub < 2; ksub++) {
      // two independent accumulator chains halve the MFMA dependency depth
      f32x16 s0 = {}, s1 = {};
      const char* krow = KsC[cur] + (ksub * 32 + ln) * 256;
      __builtin_amdgcn_s_setprio(1);
#pragma unroll
      for (int st = 0; st < 8; st += 2) {
        f16x8 kf0 = *(const f16x8*)(krow + ((st * 32 + hi * 16) ^ kfswz));
        f16x8 kf1 = *(const f16x8*)(krow + (((st + 1) * 32 + hi * 16) ^ kfswz));
        s0 = MFMA32(kf0, qf[st], s0);
        s1 = MFMA32(kf1, qf[st + 1], s1);
      }
      __builtin_amdgcn_s_setprio(0);
      f32x16 s = s0 + s1;
      int qmk = q - (k0 + ksub * 32 + 4 * hi);
      float pr[16];
#pragma unroll
      for (int r = 0; r < 16; r++) {
        float e = fast_exp2(s[r] * C1 - C2);
        if (needmask) {
          int kk = (r & 3) + 8 * (r >> 2);
          e = ((uint32_t)(qmk - kk) < 1024u) ? e : 0.0f;
        }
        lsum += e;
        pr[r] = e;
      }
      uint32_t c[8];
#pragma unroll
      for (int i = 0; i < 8; i++) c[i] = cvt_pk_u32(pr[2 * i], pr[2 * i + 1]);
      // Build PV A-fragments via shfl_xor(32) + per-lane select (validated r7).
      {
        uint32_t x0 = __shfl_xor(c[0], 32), x1 = __shfl_xor(c[1], 32);
        uint32_t x2 = __shfl_xor(c[2], 32), x3 = __shfl_xor(c[3], 32);
        u32x4 t0 = {hi ? x2 : c[0], hi ? x3 : c[1], hi ? c[2] : x0, hi ? c[3] : x1};
        pa[ksub][0] = __builtin_bit_cast(f16x8, t0);
        uint32_t x4 = __shfl_xor(c[4], 32), x5 = __shfl_xor(c[5], 32);
        uint32_t x6 = __shfl_xor(c[6], 32), x7 = __shfl_xor(c[7], 32);
        u32x4 t1 = {hi ? x6 : c[4], hi ? x7 : c[5], hi ? c[6] : x4, hi ? c[7] : x5};
        pa[ksub][1] = __builtin_bit_cast(f16x8, t1);
      }
    }
    // PV: o[q][d] += P[q][k] V[k][d]  (4 independent chains of depth 4)
    __builtin_amdgcn_s_setprio(1);
#pragma unroll
    for (int dsub = 0; dsub < 4; dsub++) {
      const char* vrow = VsC[cur] + (dsub * 32 + ln) * 128;
#pragma unroll
      for (int ksub = 0; ksub < 2; ksub++)
#pragma unroll
        for (int st2 = 0; st2 < 2; st2++) {
          f16x8 vf = *(const f16x8*)(vrow + ((ksub * 64 + st2 * 32 + hi * 16) ^ kfswz));
          o[dsub] = MFMA32(pa[ksub][st2], vf, o[dsub]);
        }
    }
    __builtin_amdgcn_s_setprio(0);
    __syncthreads();  // drains next-tile gload_lds (vmcnt) + all waves done with cur
    cur ^= 1;
  }
  // epilogue: finish l, scale, store
  lsum += __shfl_xor(lsum, 32);
  float rl[16];
#pragma unroll
  for (int r = 0; r < 16; r++) {
    int row = (r & 3) + 8 * (r >> 2) + 4 * hi;
    float lv = __shfl(lsum, row);
    rl[r] = 1.0f / lv;
  }
#pragma unroll
  for (int r = 0; r < 16; r++) {
    int row = (r & 3) + 8 * (r >> 2) + 4 * hi;
    size_t base = ((size_t)b * TT + q0 + w * 32 + row) * DM + (size_t)h * HD + ln;
#pragma unroll
    for (int dsub = 0; dsub < 4; dsub++)
      Oa[base + dsub * 32] = (f16)(o[dsub][r] * rl[r]);
  }
}

extern "C" void kernel_launch(void* const* d_in, const int* in_sizes, int n_in,
                              void* d_out, int out_size, void* d_ws, size_t ws_size,
                              hipStream_t stream) {
  const float* hidden = (const float*)d_in[0];
  const int* pos = (const int*)d_in[1];
  const float* Wq = (const float*)d_in[2];
  const float* Wk = (const float*)d_in[3];
  const float* Wv = (const float*)d_in[4];
  const float* Wo = (const float*)d_in[5];
  const float* qw = (const float*)d_in[6];
  const float* kw = (const float*)d_in[7];
  float* out = (float*)d_out;

  char* p = (char*)d_ws;
  auto take = [&](size_t n) {
    void* r = (void*)p;
    p += (n + 255) & ~(size_t)255;
    return r;
  };
  f16* Xb = (f16*)take((size_t)4096 * 2048 * 2);
  f16* WqkvT = (f16*)take((size_t)3072 * 2048 * 2);
  f16* WoT = (f16*)take((size_t)2048 * 2048 * 2);
  f16* QKVb = (f16*)take((size_t)4096 * 3072 * 2);
  f16* Qr = (f16*)take((size_t)BB * HQ * TT * HD * 2);
  f16* Kr = (f16*)take((size_t)BB * HKV * TT * HD * 2);
  f16* Vt = (f16*)take((size_t)BB * HKV * TT * HD * 2);
  f16* Attn = (f16*)take((size_t)4096 * 2048 * 2);

  dim3 tb(32, 8);
  k_cvt_f16<<<4096, 256, 0, stream>>>(hidden, Xb, 1048576);
  k_tr_all<<<10240, tb, 0, stream>>>(Wq, Wk, Wv, Wo, WqkvT, WoT);
  k_gemm8<192, 3072, true><<<256, 512, 0, stream>>>(Xb, WqkvT, QKVb, 4096, 2048);
  k_norm_rope<<<4096, 256, 0, stream>>>(QKVb, pos, qw, kw, Qr, Kr);
  k_trV<<<dim3(64, 4, 8), tb, 0, stream>>>(QKVb, Vt);
  k_attn2<<<dim3(16, 16, 2), 256, 0, stream>>>(Qr, Kr, Vt, Attn);
  k_gemm8<128, 2048, false><<<256, 512, 0, stream>>>(Attn, WoT, out, 4096, 2048);
}

// Round 14
// 190.402 us; speedup vs baseline: 1.4466x; 1.0390x over previous
//
#include <hip/hip_runtime.h>
#include <cstdint>
#include <cstddef>

#define DM 2048
#define TT 2048
#define BB 2
#define HQ 16
#define HKV 4
#define HD 128

typedef _Float16 f16;
using f16x8 = __attribute__((ext_vector_type(8))) f16;
using f32x4 = __attribute__((ext_vector_type(4))) float;
using f32x16 = __attribute__((ext_vector_type(16))) float;
using u32x4 = __attribute__((ext_vector_type(4))) uint32_t;

#define MFMA16(a, b, c) __builtin_amdgcn_mfma_f32_16x16x32_f16(a, b, c, 0, 0, 0)
#define MFMA32(a, b, c) __builtin_amdgcn_mfma_f32_32x32x16_f16(a, b, c, 0, 0, 0)

typedef __attribute__((address_space(1))) const void gvoid_t;
typedef __attribute__((address_space(3))) void lvoid_t;
static __device__ __forceinline__ void gload16(const void* g, void* l) {
  __builtin_amdgcn_global_load_lds((gvoid_t*)g, (lvoid_t*)l, 16, 0, 0);
}

static __device__ __forceinline__ float fast_exp2(float x) {
#if __has_builtin(__builtin_amdgcn_exp2f)
  return __builtin_amdgcn_exp2f(x);
#else
  return exp2f(x);
#endif
}

static __device__ __forceinline__ uint32_t cvt_pk_u32(float a, float b) {
  auto h2 = __builtin_amdgcn_cvt_pkrtz(a, b);
  return __builtin_bit_cast(uint32_t, h2);
}

// ---- prep: fp32->f16 convert of hidden  +  all weight transposes, one launch ----
__global__ __launch_bounds__(256) void k_prep(const float* __restrict__ hidden,
                                              const float* __restrict__ Wq,
                                              const float* __restrict__ Wk,
                                              const float* __restrict__ Wv,
                                              const float* __restrict__ Wo,
                                              f16* __restrict__ Xb,
                                              f16* __restrict__ WqkvT,
                                              f16* __restrict__ WoT) {
  int t = blockIdx.x;
  int tid = threadIdx.x;
  if (t < 4096) {  // convert: 8 floats per thread
    int i = t * 256 + tid;
    const float4* pin = (const float4*)hidden;
    float4 a = pin[2 * i], b = pin[2 * i + 1];
    f16x8 o = {(f16)a.x, (f16)a.y, (f16)a.z, (f16)a.w,
               (f16)b.x, (f16)b.y, (f16)b.z, (f16)b.w};
    *(f16x8*)&Xb[(size_t)8 * i] = o;
    return;
  }
  __shared__ float tile[32][33];
  t -= 4096;
  const float* in;
  f16* out;
  int N, nx;
  if (t < 4096) {
    in = Wq; out = WqkvT; N = 2048; nx = 64;
  } else if (t < 5120) {
    t -= 4096; in = Wk; out = WqkvT + (size_t)2048 * 2048; N = 512; nx = 16;
  } else if (t < 6144) {
    t -= 5120; in = Wv; out = WqkvT + (size_t)2560 * 2048; N = 512; nx = 16;
  } else {
    t -= 6144; in = Wo; out = WoT; N = 2048; nx = 64;
  }
  int n0 = (t % nx) * 32, k0 = (t / nx) * 32;
  int tx = tid & 31, ty = tid >> 5;
#pragma unroll
  for (int r = 0; r < 32; r += 8) tile[ty + r][tx] = in[(size_t)(k0 + ty + r) * N + n0 + tx];
  __syncthreads();
#pragma unroll
  for (int r = 0; r < 32; r += 8)
    out[(size_t)(n0 + ty + r) * 2048 + k0 + tx] = (f16)tile[tx][ty + r];
}

// ---- 8-phase 256xBN MFMA GEMM, barrier-light + XCD-swizzled block mapping ----
// C[M,N] = A[M,K] * BT[N,K]^T. 512 threads = 8 waves (2M x 4N), 128 x BN/4 out/wave.
template <int BN_, int N_, bool OUT_F16>
__global__ __launch_bounds__(512, 2) void k_gemm8(const f16* __restrict__ A,
                                                  const f16* __restrict__ BT,
                                                  void* __restrict__ Cp, int M, int K) {
  constexpr int NF = BN_ / 64;   // 16-col B-fragments per wave
  constexpr int BI = BN_ / 64;   // B staging issues (64 rows each)
  __shared__ alignas(16) char Abuf[2][256 * 128];  // 256 rows x 128B, linear
  __shared__ alignas(16) char Bbuf[2][BN_ * 128];
  constexpr int NT = N_ / BN_;
  // T1: XCD-aware bijective remap (gridDim.x == 256, 8 XCDs round-robin)
  int bid0 = blockIdx.x;
  int bid = (bid0 & 7) * (gridDim.x >> 3) + (bid0 >> 3);
  int m0 = (bid / NT) * 256, n0 = (bid % NT) * BN_;
  int tid = threadIdx.x;
  int lane = tid & 63, w = tid >> 6;
  int wr = w >> 2, wc = w & 3;
  int g = lane >> 4, c = lane & 15;
  int rswz = (c & 7) << 4;  // read-side XOR (fragment row&7 == c&7)

  // staging: issue i covers rows 64i..64i+63; source pre-swizzled so that
  // linear LDS[row][cb] == global[row][cb ^ ((row&7)<<4)]
  int srow = tid >> 3;                     // 0..63 within issue
  int scbs = ((tid & 7) * 16) ^ ((srow & 7) << 4);
  const char* Ag = (const char*)A + (size_t)(m0 + srow) * (K * 2) + scbs;
  const char* Bg = (const char*)BT + (size_t)(n0 + srow) * (K * 2) + scbs;
  int lbase = w * 1024;  // wave-uniform LDS base; HW adds lane*16

  f32x4 acc[8][NF] = {};
  int nk = K >> 6;

  auto stageA = [&](int buf, int kt, int i) {
    gload16(Ag + (size_t)(i * 64) * (K * 2) + (size_t)kt * 128,
            &Abuf[buf][i * 8192 + lbase]);
  };
  auto stageB = [&](int buf, int kt, int i) {
    gload16(Bg + (size_t)(i * 64) * (K * 2) + (size_t)kt * 128,
            &Bbuf[buf][i * 8192 + lbase]);
  };

  // prologue: stage K-tile 0 into buf 0, drain, publish
  {
#pragma unroll
    for (int i = 0; i < 4; i++) stageA(0, 0, i);
#pragma unroll
    for (int i = 0; i < BI; i++) stageB(0, 0, i);
    asm volatile("s_waitcnt vmcnt(0)" ::: "memory");
    __builtin_amdgcn_s_barrier();
  }

  for (int kt = 0; kt < nk; kt++) {
    int cur = kt & 1, nxt = cur ^ 1;
    bool more = (kt + 1) < nk;
    const char* Ab = Abuf[cur];
    const char* Bb = Bbuf[cur];
    f16x8 bf[NF][2], af[2][2];
#pragma unroll
    for (int p = 0; p < 4; p++) {
      if (p == 0) {
#pragma unroll
        for (int nn = 0; nn < NF; nn++)
#pragma unroll
          for (int kk = 0; kk < 2; kk++) {
            int R = wc * (NF * 16) + nn * 16 + c;
            bf[nn][kk] = *(const f16x8*)(Bb + R * 128 + ((kk * 64 + g * 16) ^ rswz));
          }
      }
#pragma unroll
      for (int j = 0; j < 2; j++)
#pragma unroll
        for (int kk = 0; kk < 2; kk++) {
          int R = wr * 128 + (p * 2 + j) * 16 + c;
          af[j][kk] = *(const f16x8*)(Ab + R * 128 + ((kk * 64 + g * 16) ^ rswz));
        }
      // issue-early: all next-tile loads go out in phases 0-1 (max slack to drain)
      if (more) {
        if (p == 0) {
          stageA(nxt, kt + 1, 0); stageA(nxt, kt + 1, 1); stageB(nxt, kt + 1, 0);
        } else if (p == 1) {
          stageA(nxt, kt + 1, 2); stageA(nxt, kt + 1, 3); stageB(nxt, kt + 1, 1);
          if constexpr (BI == 3) stageB(nxt, kt + 1, 2);
        }
      }
      __builtin_amdgcn_s_barrier();  // pre-MFMA lockstep (no post-MFMA barrier:
                                     // phase p+1 ds_reads overlap phase p MFMA)
      __builtin_amdgcn_s_setprio(1);
#pragma unroll
      for (int j = 0; j < 2; j++)
#pragma unroll
        for (int nn = 0; nn < NF; nn++)
#pragma unroll
          for (int kk = 0; kk < 2; kk++)
            acc[p * 2 + j][nn] = MFMA16(af[j][kk], bf[nn][kk], acc[p * 2 + j][nn]);
      __builtin_amdgcn_s_setprio(0);
    }
    // K-tile boundary: the only full drain — next tile's LDS image must be
    // complete (vmcnt) and all waves done reading buf[cur] (barrier).
    asm volatile("s_waitcnt vmcnt(0)" ::: "memory");
    __builtin_amdgcn_s_barrier();
  }
  // epilogue: C-write
#pragma unroll
  for (int mm = 0; mm < 8; mm++)
#pragma unroll
    for (int nn = 0; nn < NF; nn++)
#pragma unroll
      for (int r = 0; r < 4; r++) {
        size_t row = m0 + wr * 128 + mm * 16 + g * 4 + r;
        size_t col = n0 + wc * (NF * 16) + nn * 16 + c;
        float v = acc[mm][nn][r];
        if constexpr (OUT_F16)
          ((f16*)Cp)[row * N_ + col] = (f16)v;
        else
          ((float*)Cp)[row * N_ + col] = v;
      }
}

// ---- post-QKV: RMSNorm+RoPE (Q,K) and V transpose, one launch ----
__global__ __launch_bounds__(256) void k_post(const f16* __restrict__ qkv,
                                              const int* __restrict__ pos_ids,
                                              const float* __restrict__ qw,
                                              const float* __restrict__ kw,
                                              f16* __restrict__ Qo, f16* __restrict__ Ko,
                                              f16* __restrict__ Vt) {
  int blk = blockIdx.x;
  int tid = threadIdx.x;
  if (blk < 4096) {  // norm+rope
    int bt = blk;
    int b = bt >> 11, t = bt & 2047;
    int w = tid >> 6, lane = tid & 63;
    const f16* row = qkv + (size_t)bt * 3072;
    float pq = (float)pos_ids[t];
    float pk = (float)t;
    float inv = expf(-(float)lane * 0.14391156831212787f);
    float aq = pq * inv, ak = pk * inv;
    float snq = sinf(aq), csq = cosf(aq);
    float snk = sinf(ak), csk = cosf(ak);
    for (int hi = w; hi < 20; hi += 4) {
      bool isq = hi < 16;
      int off = isq ? hi * 128 : 2048 + (hi - 16) * 128;
      float x1 = (float)row[off + 2 * lane];
      float x2 = (float)row[off + 2 * lane + 1];
      float ss = x1 * x1 + x2 * x2;
#pragma unroll
      for (int o = 1; o < 64; o <<= 1) ss += __shfl_xor(ss, o);
      float rms = rsqrtf(ss * (1.0f / 128.0f) + 1e-6f);
      const float* wt = isq ? qw : kw;
      float n1 = x1 * rms * wt[2 * lane], n2 = x2 * rms * wt[2 * lane + 1];
      float sn = isq ? snq : snk, cs = isq ? csq : csk;
      f16 r1 = (f16)(n1 * cs - n2 * sn), r2 = (f16)(n1 * sn + n2 * cs);
      if (isq) {
        f16* dst = Qo + (((size_t)b * HQ + hi) * TT + t) * HD;
        dst[2 * lane] = r1;
        dst[2 * lane + 1] = r2;
      } else {
        f16* dst = Ko + (((size_t)b * HKV + (hi - 16)) * TT + t) * HD;
        dst[2 * lane] = r1;
        dst[2 * lane + 1] = r2;
      }
    }
    return;
  }
  // V transpose: Vt[b][hkv][d][t]
  __shared__ f16 tile[32][34];
  int t2 = blk - 4096;
  int t0 = (t2 & 63) * 32, d0 = ((t2 >> 6) & 3) * 32;
  int bh = t2 >> 8;
  int b = bh >> 2, hkv = bh & 3;
  int tx = tid & 31, ty = tid >> 5;
  const f16* src = qkv + (size_t)b * 2048 * 3072 + 2560 + hkv * 128;
#pragma unroll
  for (int r = 0; r < 32; r += 8)
    tile[ty + r][tx] = src[(size_t)(t0 + ty + r) * 3072 + d0 + tx];
  __syncthreads();
  f16* dst = Vt + ((size_t)bh * HD + d0) * TT + t0;
#pragma unroll
  for (int r = 0; r < 32; r += 8)
    dst[(size_t)(ty + r) * TT + tx] = tile[tx][ty + r];
}

// ---- attention: 4 waves x 32q, 64-key tiles, swapped QK^T, gload_lds dbuf staging ----
__global__ __launch_bounds__(256, 2) void k_attn2(const f16* __restrict__ Q,
                                                  const f16* __restrict__ Kc,
                                                  const f16* __restrict__ Vt,
                                                  f16* __restrict__ Oa) {
  // double-buffered tiles; LDS linear, swizzle applied on GLOBAL source + on read
  __shared__ alignas(16) char KsC[2][64 * 256];   // K: 64 keys x 128 d (256B rows)
  __shared__ alignas(16) char VsC[2][128 * 128];  // V^T: 128 d x 64 keys (128B rows)
  int qt = blockIdx.x, h = blockIdx.y, b = blockIdx.z;
  // balance remap (r11, measured best): blocks i and i+256 share a CU and differ
  // only in b -> pair (qt, 15-qt)
  qt = b ? (15 - qt) : qt;
  int q0 = qt * 128, hkv = h >> 2;
  int tid = threadIdx.x;
  int w = tid >> 6, lane = tid & 63, ln = lane & 31, hi = lane >> 5;
  const char* KbB = (const char*)(Kc + ((size_t)b * HKV + hkv) * TT * HD);
  const char* VbB = (const char*)(Vt + ((size_t)b * HKV + hkv) * (size_t)HD * TT);
  int q = q0 + w * 32 + ln;
  const f16* Qp = Q + (((size_t)b * HQ + h) * TT + q) * HD + hi * 8;
  f16x8 qf[8];
#pragma unroll
  for (int st = 0; st < 8; st++) qf[st] = *(const f16x8*)&Qp[st * 16];
  f32x16 o[4] = {};
  float lsum = 0.f;
  int kfswz = (ln & 7) << 4;

  // staging source addressing (dest linear: byte = j*4096 + w*1024 + lane*16)
  int krow0 = w * 4 + (lane >> 4);                       // + j*16 per issue
  int kswzb = ((lane & 15) * 16) ^ ((krow0 & 7) << 4);   // pre-swizzled col byte
  int vrow0 = w * 8 + (lane >> 3);                       // + j*32 per issue
  int vswzb = ((lane & 7) * 16) ^ ((vrow0 & 7) << 4);

  int k0max = (q0 + 127) & ~63;
  int wlo = (q0 - 1023 > 128) ? ((q0 - 1023) & ~63) : 128;
  int nw = (k0max >= wlo) ? ((k0max - wlo) >> 6) + 1 : 0;
  int ntiles = 2 + nw;
  int qw = q0 + w * 32;

  const float C1 = 0.12751791217100872f;  // (1/sqrt(128)) * log2(e)
  const float C2 = 5.7707801635534255f;   // 4.0 * log2(e)  (fixed softmax shift)

  auto stage = [&](int buf, int k0) {
    const char* ks = KbB + (size_t)(k0 + krow0) * 256 + kswzb;
    const char* vs = VbB + (size_t)vrow0 * (TT * 2) + (size_t)k0 * 2 + vswzb;
    char* kd = KsC[buf] + w * 1024;
    char* vd = VsC[buf] + w * 1024;
#pragma unroll
    for (int j = 0; j < 4; j++) gload16(ks + (size_t)j * 4096, kd + j * 4096);
#pragma unroll
    for (int j = 0; j < 4; j++) gload16(vs + (size_t)j * 32 * (TT * 2), vd + j * 4096);
  };

  stage(0, 0);
  __syncthreads();
  int cur = 0;

  for (int ti = 0; ti < ntiles; ti++) {
    int k0 = (ti < 2) ? ti * 64 : wlo + (ti - 2) * 64;
    bool havenext = (ti + 1 < ntiles);
    if (havenext) {  // async loads for next tile; hidden under this tile's compute
      int k0n = (ti + 1 < 2) ? 64 : wlo + (ti - 1) * 64;
      stage(cur ^ 1, k0n);
    }
    bool needmask = false;
    if (ti >= 2) {
      int wsmax = qw + 31 - 1023;
      if (wsmax < 128) wsmax = 128;
      needmask = !((k0 + 63 <= qw) && (k0 >= wsmax));
    }
    f16x8 pa[2][2];
#pragma unroll
    for (int ksub = 0; ksub < 2; ksub++) {
      // two independent accumulator chains halve the MFMA dependency depth
      f32x16 s0 = {}, s1 = {};
      const char* krow = KsC[cur] + (ksub * 32 + ln) * 256;
      __builtin_amdgcn_s_setprio(1);
#pragma unroll
      for (int st = 0; st < 8; st += 2) {
        f16x8 kf0 = *(const f16x8*)(krow + ((st * 32 + hi * 16) ^ kfswz));
        f16x8 kf1 = *(const f16x8*)(krow + (((st + 1) * 32 + hi * 16) ^ kfswz));
        s0 = MFMA32(kf0, qf[st], s0);
        s1 = MFMA32(kf1, qf[st + 1], s1);
      }
      __builtin_amdgcn_s_setprio(0);
      f32x16 s = s0 + s1;
      int qmk = q - (k0 + ksub * 32 + 4 * hi);
      float pr[16];
#pragma unroll
      for (int r = 0; r < 16; r++) {
        float e = fast_exp2(s[r] * C1 - C2);
        if (needmask) {
          int kk = (r & 3) + 8 * (r >> 2);
          e = ((uint32_t)(qmk - kk) < 1024u) ? e : 0.0f;
        }
        lsum += e;
        pr[r] = e;
      }
      uint32_t c[8];
#pragma unroll
      for (int i = 0; i < 8; i++) c[i] = cvt_pk_u32(pr[2 * i], pr[2 * i + 1]);
      // Build PV A-fragments via shfl_xor(32) + per-lane select (validated r7).
      {
        uint32_t x0 = __shfl_xor(c[0], 32), x1 = __shfl_xor(c[1], 32);
        uint32_t x2 = __shfl_xor(c[2], 32), x3 = __shfl_xor(c[3], 32);
        u32x4 t0 = {hi ? x2 : c[0], hi ? x3 : c[1], hi ? c[2] : x0, hi ? c[3] : x1};
        pa[ksub][0] = __builtin_bit_cast(f16x8, t0);
        uint32_t x4 = __shfl_xor(c[4], 32), x5 = __shfl_xor(c[5], 32);
        uint32_t x6 = __shfl_xor(c[6], 32), x7 = __shfl_xor(c[7], 32);
        u32x4 t1 = {hi ? x6 : c[4], hi ? x7 : c[5], hi ? c[6] : x4, hi ? c[7] : x5};
        pa[ksub][1] = __builtin_bit_cast(f16x8, t1);
      }
    }
    // PV: o[q][d] += P[q][k] V[k][d]  (4 independent chains of depth 4)
    __builtin_amdgcn_s_setprio(1);
#pragma unroll
    for (int dsub = 0; dsub < 4; dsub++) {
      const char* vrow = VsC[cur] + (dsub * 32 + ln) * 128;
#pragma unroll
      for (int ksub = 0; ksub < 2; ksub++)
#pragma unroll
        for (int st2 = 0; st2 < 2; st2++) {
          f16x8 vf = *(const f16x8*)(vrow + ((ksub * 64 + st2 * 32 + hi * 16) ^ kfswz));
          o[dsub] = MFMA32(pa[ksub][st2], vf, o[dsub]);
        }
    }
    __builtin_amdgcn_s_setprio(0);
    __syncthreads();  // drains next-tile gload_lds (vmcnt) + all waves done with cur
    cur ^= 1;
  }
  // epilogue: finish l, scale, store
  lsum += __shfl_xor(lsum, 32);
  float rl[16];
#pragma unroll
  for (int r = 0; r < 16; r++) {
    int row = (r & 3) + 8 * (r >> 2) + 4 * hi;
    float lv = __shfl(lsum, row);
    rl[r] = 1.0f / lv;
  }
#pragma unroll
  for (int r = 0; r < 16; r++) {
    int row = (r & 3) + 8 * (r >> 2) + 4 * hi;
    size_t base = ((size_t)b * TT + q0 + w * 32 + row) * DM + (size_t)h * HD + ln;
#pragma unroll
    for (int dsub = 0; dsub < 4; dsub++)
      Oa[base + dsub * 32] = (f16)(o[dsub][r] * rl[r]);
  }
}

extern "C" void kernel_launch(void* const* d_in, const int* in_sizes, int n_in,
                              void* d_out, int out_size, void* d_ws, size_t ws_size,
                              hipStream_t stream) {
  const float* hidden = (const float*)d_in[0];
  const int* pos = (const int*)d_in[1];
  const float* Wq = (const float*)d_in[2];
  const float* Wk = (const float*)d_in[3];
  const float* Wv = (const float*)d_in[4];
  const float* Wo = (const float*)d_in[5];
  const float* qw = (const float*)d_in[6];
  const float* kw = (const float*)d_in[7];
  float* out = (float*)d_out;

  char* p = (char*)d_ws;
  auto take = [&](size_t n) {
    void* r = (void*)p;
    p += (n + 255) & ~(size_t)255;
    return r;
  };
  f16* Xb = (f16*)take((size_t)4096 * 2048 * 2);
  f16* WqkvT = (f16*)take((size_t)3072 * 2048 * 2);
  f16* WoT = (f16*)take((size_t)2048 * 2048 * 2);
  f16* QKVb = (f16*)take((size_t)4096 * 3072 * 2);
  f16* Qr = (f16*)take((size_t)BB * HQ * TT * HD * 2);
  f16* Kr = (f16*)take((size_t)BB * HKV * TT * HD * 2);
  f16* Vt = (f16*)take((size_t)BB * HKV * TT * HD * 2);
  f16* Attn = (f16*)take((size_t)4096 * 2048 * 2);

  k_prep<<<14336, 256, 0, stream>>>(hidden, Wq, Wk, Wv, Wo, Xb, WqkvT, WoT);
  k_gemm8<192, 3072, true><<<256, 512, 0, stream>>>(Xb, WqkvT, QKVb, 4096, 2048);
  k_post<<<6144, 256, 0, stream>>>(QKVb, pos, qw, kw, Qr, Kr, Vt);
  k_attn2<<<dim3(16, 16, 2), 256, 0, stream>>>(Qr, Kr, Vt, Attn);
  k_gemm8<128, 2048, false><<<256, 512, 0, stream>>>(Attn, WoT, out, 4096, 2048);
}